// Round 5
// baseline (1415.744 us; speedup 1.0000x reference)
//
#include <hip/hip_runtime.h>
#include <cstdint>

// ---------------------------------------------------------------------------
// RWKV7 block (B=4,T=1024,C=2048,H=32,N=64,DFF=8192) for MI355X gfx950.
// R5: WKV scan with 16-way k-split (2048 blocks -> 2 waves/SIMD TLP),
//     pure-DPP 16-lane reductions (quad_perm + row_ror), depth-8 reg prefetch.
// ---------------------------------------------------------------------------

typedef __attribute__((ext_vector_type(4))) float f32x4;
typedef __attribute__((ext_vector_type(8))) __bf16 bf16x8;
typedef __attribute__((ext_vector_type(8))) unsigned short us8;

#define DEV __device__ __forceinline__

DEV unsigned short f2b(float f) {
  union { float f; unsigned u; } v; v.f = f;
  unsigned r = v.u + 0x7fffu + ((v.u >> 16) & 1u);
  return (unsigned short)(r >> 16);
}
DEV float b2f(unsigned short u) {
  union { unsigned u; float f; } v; v.u = (unsigned)u << 16;
  return v.f;
}

DEV void gload16(const void* g, void* l) {
  void* gg = const_cast<void*>(g);
  __builtin_amdgcn_global_load_lds(
      (__attribute__((address_space(1))) unsigned int*)gg,
      (__attribute__((address_space(3))) unsigned int*)l, 16, 0, 0);
}

DEV float red8(float v) {  // sum over aligned 8-lane group
  v += __shfl_xor(v, 1);
  v += __shfl_xor(v, 2);
  v += __shfl_xor(v, 4);
  return v;
}

// ------------------------------ weight prep --------------------------------

__global__ void k_transpose(const float* __restrict__ src,
                            unsigned short* __restrict__ dst, int R, int Cc) {
  __shared__ float tile[32][33];
  const int c0 = blockIdx.x * 32, r0 = blockIdx.y * 32;
  const int tx = threadIdx.x, ty = threadIdx.y;  // block (32,8)
  for (int i = ty; i < 32; i += 8)
    tile[i][tx] = src[(size_t)(r0 + i) * Cc + c0 + tx];
  __syncthreads();
  for (int i = ty; i < 32; i += 8)
    dst[(size_t)(c0 + i) * R + r0 + tx] = f2b(tile[tx][i]);
}

// Wcat^T [384][4096]: rows j: [w1|a1|v1|g1] col j; cols c: c<2048 -> W[c][j],
// c>=2048 -> mix[c-2048]*W[c-2048][j]. Rows 288..383 zero-padded.
__global__ void k_wcat(const float* __restrict__ w1, const float* __restrict__ a1,
                       const float* __restrict__ v1, const float* __restrict__ g1,
                       const float* __restrict__ xw, const float* __restrict__ xa,
                       const float* __restrict__ xv, const float* __restrict__ xg,
                       unsigned short* __restrict__ dst) {
  const int i = blockIdx.x * 256 + threadIdx.x;
  if (i >= 384 * 4096) return;
  const int j = i >> 12, c = i & 4095;
  float val = 0.f;
  if (j < 288) {
    const float* W; const float* mix; int jj, D;
    if (j < 64)       { W = w1; mix = xw; jj = j;       D = 64;  }
    else if (j < 128) { W = a1; mix = xa; jj = j - 64;  D = 64;  }
    else if (j < 160) { W = v1; mix = xv; jj = j - 128; D = 32;  }
    else              { W = g1; mix = xg; jj = j - 160; D = 128; }
    const int cc = c & 2047;
    val = W[(size_t)cc * D + jj];
    if (c >= 2048) val *= mix[cc];
  }
  dst[i] = f2b(val);
}

// ------------------------------ LN + mix -----------------------------------

DEV void breduce2(float& a, float& b, float* rbuf) {
#pragma unroll
  for (int m = 1; m < 64; m <<= 1) { a += __shfl_xor(a, m); b += __shfl_xor(b, m); }
  const int wid = threadIdx.x >> 6, lane = threadIdx.x & 63;
  if (lane == 0) { rbuf[wid] = a; rbuf[4 + wid] = b; }
  __syncthreads();
  a = rbuf[0] + rbuf[1] + rbuf[2] + rbuf[3];
  b = rbuf[4] + rbuf[5] + rbuf[6] + rbuf[7];
  __syncthreads();
}

__global__ __launch_bounds__(256)
void k_ln1_mix(const float* __restrict__ x, const float* __restrict__ shift,
               const float* __restrict__ lw, const float* __restrict__ lb,
               const float* __restrict__ mr, const float* __restrict__ mk,
               const float* __restrict__ mv,
               unsigned short* __restrict__ A2, unsigned short* __restrict__ xrb,
               unsigned short* __restrict__ xkb, unsigned short* __restrict__ xvb) {
  __shared__ float rbuf[8];
  const int m = blockIdx.x, tid = threadIdx.x;
  const int b = m >> 10, t = m & 1023;
  const float* xt = x + (size_t)m * 2048 + tid * 8;
  const float* xp = (t > 0) ? (x + (size_t)(m - 1) * 2048 + tid * 8)
                            : (shift + (size_t)b * 2048 + tid * 8);
  float vt[8], vp[8];
  *(float4*)&vt[0] = *(const float4*)(xt);
  *(float4*)&vt[4] = *(const float4*)(xt + 4);
  *(float4*)&vp[0] = *(const float4*)(xp);
  *(float4*)&vp[4] = *(const float4*)(xp + 4);
  float st = 0.f, sp = 0.f;
#pragma unroll
  for (int i = 0; i < 8; ++i) { st += vt[i]; sp += vp[i]; }
  breduce2(st, sp, rbuf);
  const float mt_ = st * (1.f / 2048.f), mp_ = sp * (1.f / 2048.f);
  float qt = 0.f, qp = 0.f;
#pragma unroll
  for (int i = 0; i < 8; ++i) {
    float d0 = vt[i] - mt_; qt += d0 * d0;
    float d1 = vp[i] - mp_; qp += d1 * d1;
  }
  breduce2(qt, qp, rbuf);
  const float rt = rsqrtf(qt * (1.f / 2048.f) + 1e-5f);
  const float rp = rsqrtf(qp * (1.f / 2048.f) + 1e-5f);
  const bool lnp = (t > 0);
#pragma unroll
  for (int i = 0; i < 8; ++i) {
    const int c = tid * 8 + i;
    const float wv = lw[c], bv = lb[c];
    const float xn = (vt[i] - mt_) * rt * wv + bv;
    const float pn = lnp ? ((vp[i] - mp_) * rp * wv + bv) : vp[i];
    const float xx = pn - xn;
    A2[(size_t)m * 4096 + c] = f2b(xn);
    A2[(size_t)m * 4096 + 2048 + c] = f2b(xx);
    xrb[(size_t)m * 2048 + c] = f2b(xn + xx * mr[c]);
    xkb[(size_t)m * 2048 + c] = f2b(xn + xx * mk[c]);
    xvb[(size_t)m * 2048 + c] = f2b(xn + xx * mv[c]);
  }
}

__global__ __launch_bounds__(256)
void k_ln2_mix(const float* __restrict__ x1, const float* __restrict__ shift,
               const float* __restrict__ lw, const float* __restrict__ lb,
               const float* __restrict__ mk, unsigned short* __restrict__ xkf) {
  __shared__ float rbuf[8];
  const int m = blockIdx.x, tid = threadIdx.x;
  const int b = m >> 10, t = m & 1023;
  const float* xt = x1 + (size_t)m * 2048 + tid * 8;
  const float* xp = (t > 0) ? (x1 + (size_t)(m - 1) * 2048 + tid * 8)
                            : (shift + (size_t)b * 2048 + tid * 8);
  float vt[8], vp[8];
  *(float4*)&vt[0] = *(const float4*)(xt);
  *(float4*)&vt[4] = *(const float4*)(xt + 4);
  *(float4*)&vp[0] = *(const float4*)(xp);
  *(float4*)&vp[4] = *(const float4*)(xp + 4);
  float st = 0.f, sp = 0.f;
#pragma unroll
  for (int i = 0; i < 8; ++i) { st += vt[i]; sp += vp[i]; }
  breduce2(st, sp, rbuf);
  const float mt_ = st * (1.f / 2048.f), mp_ = sp * (1.f / 2048.f);
  float qt = 0.f, qp = 0.f;
#pragma unroll
  for (int i = 0; i < 8; ++i) {
    float d0 = vt[i] - mt_; qt += d0 * d0;
    float d1 = vp[i] - mp_; qp += d1 * d1;
  }
  breduce2(qt, qp, rbuf);
  const float rt = rsqrtf(qt * (1.f / 2048.f) + 1e-5f);
  const float rp = rsqrtf(qp * (1.f / 2048.f) + 1e-5f);
  const bool lnp = (t > 0);
#pragma unroll
  for (int i = 0; i < 8; ++i) {
    const int c = tid * 8 + i;
    const float wv = lw[c], bv = lb[c];
    const float xn = (vt[i] - mt_) * rt * wv + bv;
    const float pn = lnp ? ((vp[i] - mp_) * rp * wv + bv) : vp[i];
    xkf[(size_t)m * 2048 + c] = f2b(xn + (pn - xn) * mk[c]);
  }
}

// ------------------------------ GEMM (bf16 MFMA) ---------------------------
// C[M,N] = A[M,K] @ B[K,N], A bf16 row-major (lda), Bt = B^T bf16 [N][K] (ldb).
// 128x128 tile, BK=32, 256 thr = 4 waves 2x2, each wave 64x64 (4x4 mfma).

constexpr int EP_F32 = 0, EP_B16 = 1, EP_W = 2, EP_AB16 = 3, EP_VGB16 = 4,
              EP_RELU2 = 5, EP_ADDF = 6, EP_HACT = 7;

template <int EP>
DEV void ep_store(float acc, long row, long c, long ldc, float* Co,
                  unsigned short* Cob, const float* bias, const float* e0f,
                  const unsigned short* e0b) {
  const long idx = row * ldc + c;
  if constexpr (EP == EP_F32) {
    Co[idx] = acc;
  } else if constexpr (EP == EP_B16) {
    Cob[idx] = f2b(acc);
  } else if constexpr (EP == EP_W) {
    const float wv = bias[c] + acc;
    const float sp = log1pf(expf(-wv));        // softplus(-wv)
    const float w = -sp - 0.5f;
    Co[idx] = expf(-expf(w));                  // decay in (0,1), f32
  } else if constexpr (EP == EP_AB16) {
    Cob[idx] = f2b(1.f / (1.f + expf(-(bias[c] + acc))));
  } else if constexpr (EP == EP_VGB16) {
    const float s = 1.f / (1.f + expf(-(bias[c] + acc)));
    const float vv = b2f(e0b[idx]);
    Cob[idx] = f2b(vv + (e0f[idx] - vv) * s);
  } else if constexpr (EP == EP_RELU2) {
    const float r = fmaxf(acc, 0.f);
    Cob[idx] = f2b(r * r);
  } else if constexpr (EP == EP_ADDF) {
    Co[idx] = acc + e0f[idx];
  } else if constexpr (EP == EP_HACT) {
    float vv = acc;
    if (c < 64) vv = tanhf(vv);                      // w path
    else if (c >= 160) vv = 1.f / (1.f + expf(-vv)); // g path
    Cob[idx] = f2b(vv);
  }
}

template <int EP>
__global__ __launch_bounds__(256)
void gemm_bt(const unsigned short* __restrict__ A, long lda,
             const unsigned short* __restrict__ Bt, long ldb, long N, long K,
             long ldc, float* __restrict__ Co, unsigned short* __restrict__ Cob,
             const float* __restrict__ bias, const float* __restrict__ e0f,
             const unsigned short* __restrict__ e0b) {
  __shared__ unsigned short As[4096];  // [128][32]
  __shared__ unsigned short Bs[4096];  // [128][32]
  const int tid = threadIdx.x;
  const int wid = tid >> 6, lane = tid & 63;
  const long row0 = (long)blockIdx.x * 128, col0 = (long)blockIdx.y * 128;
  const int wm = (wid >> 1) * 64, wn = (wid & 1) * 64;
  f32x4 acc[4][4] = {};
  const int sr = tid >> 2, sk = (tid & 3) * 8;
  const unsigned short* gA = A + (row0 + sr) * lda + sk;
  const unsigned short* gB = Bt + (col0 + sr) * ldb + sk;
  unsigned short* lA = As + wid * 512;
  unsigned short* lB = Bs + wid * 512;
  const int fr = lane & 15, fk = (lane >> 4) * 8;

  for (long kb = 0; kb < K; kb += 32) {
    gload16(gA + kb, lA);
    gload16(gA + kb + 64 * lda, lA + 2048);
    gload16(gB + kb, lB);
    gload16(gB + kb + 64 * ldb, lB + 2048);
    __syncthreads();  // drains vmcnt before barrier (m97 structure)
    bf16x8 af[4], bq[4];
#pragma unroll
    for (int mt = 0; mt < 4; ++mt)
      af[mt] = *(const bf16x8*)(As + (wm + mt * 16 + fr) * 32 + fk);
#pragma unroll
    for (int nt = 0; nt < 4; ++nt)
      bq[nt] = *(const bf16x8*)(Bs + (wn + nt * 16 + fr) * 32 + fk);
#pragma unroll
    for (int mt = 0; mt < 4; ++mt)
#pragma unroll
      for (int nt = 0; nt < 4; ++nt)
        acc[mt][nt] = __builtin_amdgcn_mfma_f32_16x16x32_bf16(
            af[mt], bq[nt], acc[mt][nt], 0, 0, 0);
    __syncthreads();
  }
  const int fq = lane >> 4;
#pragma unroll
  for (int mt = 0; mt < 4; ++mt) {
#pragma unroll
    for (int nt = 0; nt < 4; ++nt) {
      const long c = col0 + wn + nt * 16 + fr;
      if (c < N) {
        const long rb = row0 + wm + mt * 16 + fq * 4;
#pragma unroll
        for (int rg = 0; rg < 4; ++rg)
          ep_store<EP>(acc[mt][nt][rg], rb + rg, c, ldc, Co, Cob, bias, e0f, e0b);
      }
    }
  }
}

// ------------------------------ k_post -------------------------------------
// kk normalize: kio(raw k)->kh in place; abio(a)->bb in place; aao <- -kk.
__global__ __launch_bounds__(256)
void k_post(unsigned short* __restrict__ kio, unsigned short* __restrict__ abio,
            unsigned short* __restrict__ aao, const float* __restrict__ kkw,
            const float* __restrict__ kaw) {
  const int m = blockIdx.x, tid = threadIdx.x;
  const size_t base = (size_t)m * 2048 + tid * 8;
  us8 k8 = *(const us8*)(kio + base);
  us8 a8 = *(const us8*)(abio + base);
  float kk8[8], ka8[8];
  *(float4*)&kk8[0] = *(const float4*)(kkw + tid * 8);
  *(float4*)&kk8[4] = *(const float4*)(kkw + tid * 8 + 4);
  *(float4*)&ka8[0] = *(const float4*)(kaw + tid * 8);
  *(float4*)&ka8[4] = *(const float4*)(kaw + tid * 8 + 4);
  float kx[8], kv[8], av[8];
  float ss = 0.f;
#pragma unroll
  for (int i = 0; i < 8; ++i) {
    kv[i] = b2f(k8[i]); av[i] = b2f(a8[i]);
    kx[i] = kv[i] * kk8[i]; ss += kx[i] * kx[i];
  }
  ss = red8(ss);  // per-head (64 ch = 8 lanes)
  const float inv = 1.f / fmaxf(sqrtf(ss), 1e-12f);
  us8 kh8, aa8, bb8;
#pragma unroll
  for (int i = 0; i < 8; ++i) {
    const float kkn = kx[i] * inv;
    kh8[i] = f2b(kv[i] * (1.f + (av[i] - 1.f) * ka8[i]));
    aa8[i] = f2b(-kkn);
    bb8[i] = f2b(kkn * av[i]);
  }
  *(us8*)(kio + base) = kh8;
  *(us8*)(aao + base) = aa8;
  *(us8*)(abio + base) = bb8;
}

// ------------------------------ WKV scan -----------------------------------
// 2048 blocks x 64 threads (1 wave). block = (bh, rq): 4 value-rows.
// lane = rl*16 + kg; kg (0..15) owns 4 k's, rl (0..3) one row.
// Streams load straight into VGPRs, depth-8 named double-buffers.
// 16-lane k-reduction via pure DPP: quad_perm xor1, xor2, row_ror:4, row_ror:8.

DEV float red16(float x) {  // all-lanes sum within each 16-lane row
  union { float f; int i; } a, r;
  a.f = x; r.i = __builtin_amdgcn_update_dpp(0, a.i, 0xB1, 0xf, 0xf, true);  // quad xor1
  x += r.f;
  a.f = x; r.i = __builtin_amdgcn_update_dpp(0, a.i, 0x4E, 0xf, 0xf, true);  // quad xor2
  x += r.f;
  a.f = x; r.i = __builtin_amdgcn_update_dpp(0, a.i, 0x124, 0xf, 0xf, true); // row_ror:4
  x += r.f;
  a.f = x; r.i = __builtin_amdgcn_update_dpp(0, a.i, 0x128, 0xf, 0xf, true); // row_ror:8
  x += r.f;
  return x;
}

DEV void cv4(const uint2 q, float* o) {  // 4 bf16 (2 dwords) -> 4 f32
  union { unsigned u; float f; } t;
  t.u = q.x << 16;          o[0] = t.f;
  t.u = q.x & 0xffff0000u;  o[1] = t.f;
  t.u = q.y << 16;          o[2] = t.f;
  t.u = q.y & 0xffff0000u;  o[3] = t.f;
}

__global__ __launch_bounds__(64)
void k_scan(const unsigned short* __restrict__ rp,
            const unsigned short* __restrict__ kp,
            const unsigned short* __restrict__ vp,
            const float* __restrict__ wp,
            const unsigned short* __restrict__ ap,
            const unsigned short* __restrict__ bp,
            const float* __restrict__ s0, float* __restrict__ yout,
            float* __restrict__ snew) {
  __shared__ float ylds[1024][4];  // 16 KiB
  const int lane = threadIdx.x;
  const int bh = blockIdx.x & 127;   // siblings bh+128*rq -> same XCD (mod 8)
  const int rq = blockIdx.x >> 7;    // 0..15
  const int b = bh >> 5, h = bh & 31;
  const int kg = lane & 15, rl = lane >> 4;
  const int v = rq * 4 + rl, ks = kg * 4;
  const size_t off_bh = (size_t)b * 1024 * 2048 + (size_t)h * 64;

  const unsigned short* prb = rp + off_bh + ks;
  const unsigned short* pkb = kp + off_bh + ks;
  const unsigned short* pab = ap + off_bh + ks;
  const unsigned short* pbb = bp + off_bh + ks;
  const float*          pwb = wp + off_bh + ks;
  const unsigned short* pvb = vp + off_bh + v;

  float S[4];
  *(float4*)&S[0] = *(const float4*)(s0 + (((size_t)bh * 64 + v) * 64 + ks));

  uint2 r0_, k0_, a0_, b0_, r1_, k1_, a1_, b1_;
  uint2 r2_, k2_, a2_, b2_, r3_, k3_, a3_, b3_;
  uint2 r4_, k4_, a4_, b4_, r5_, k5_, a5_, b5_;
  uint2 r6_, k6_, a6_, b6_, r7_, k7_, a7_, b7_;
  float4 w0_, w1_, w2_, w3_, w4_, w5_, w6_, w7_;
  unsigned short f0_, f1_, f2_, f3_, f4_, f5_, f6_, f7_;

#define SLOAD(Br, Bk, Ba, Bb, Bw, Bf, T)                                     \
  {                                                                          \
    const size_t o_ = (size_t)(T) * 2048;                                    \
    Br = *(const uint2*)(prb + o_);  Bk = *(const uint2*)(pkb + o_);         \
    Ba = *(const uint2*)(pab + o_);  Bb = *(const uint2*)(pbb + o_);         \
    Bw = *(const float4*)(pwb + o_); Bf = pvb[o_];                           \
  }

  SLOAD(r0_, k0_, a0_, b0_, w0_, f0_, 0)
  SLOAD(r1_, k1_, a1_, b1_, w1_, f1_, 1)
  SLOAD(r2_, k2_, a2_, b2_, w2_, f2_, 2)
  SLOAD(r3_, k3_, a3_, b3_, w3_, f3_, 3)
  SLOAD(r4_, k4_, a4_, b4_, w4_, f4_, 4)
  SLOAD(r5_, k5_, a5_, b5_, w5_, f5_, 5)
  SLOAD(r6_, k6_, a6_, b6_, w6_, f6_, 6)
  SLOAD(r7_, k7_, a7_, b7_, w7_, f7_, 7)

#define SBODY(T, Br, Bk, Ba, Bb, Bw, Bf)                                     \
  {                                                                          \
    float rr[4], kk[4], av[4], bv[4];                                        \
    cv4(Br, rr); cv4(Bk, kk); cv4(Ba, av); cv4(Bb, bv);                      \
    const float4 wf = Bw;                                                    \
    const float vv = b2f(Bf);                                                \
    int tn_ = (T) + 8; if (tn_ > 1023) tn_ = 1023;                           \
    SLOAD(Br, Bk, Ba, Bb, Bw, Bf, tn_)                                       \
    float sa = S[0] * av[0] + S[1] * av[1] + S[2] * av[2] + S[3] * av[3];    \
    sa = red16(sa);                                                          \
    float y;                                                                 \
    S[0] = S[0] * wf.x + sa * bv[0] + vv * kk[0]; y  = S[0] * rr[0];         \
    S[1] = S[1] * wf.y + sa * bv[1] + vv * kk[1]; y += S[1] * rr[1];         \
    S[2] = S[2] * wf.z + sa * bv[2] + vv * kk[2]; y += S[2] * rr[2];         \
    S[3] = S[3] * wf.w + sa * bv[3] + vv * kk[3]; y += S[3] * rr[3];         \
    y = red16(y);                                                            \
    if (kg == 0) ylds[T][rl] = y;                                            \
  }

  for (int tb = 0; tb < 1024; tb += 8) {
    SBODY(tb + 0, r0_, k0_, a0_, b0_, w0_, f0_)
    SBODY(tb + 1, r1_, k1_, a1_, b1_, w1_, f1_)
    SBODY(tb + 2, r2_, k2_, a2_, b2_, w2_, f2_)
    SBODY(tb + 3, r3_, k3_, a3_, b3_, w3_, f3_)
    SBODY(tb + 4, r4_, k4_, a4_, b4_, w4_, f4_)
    SBODY(tb + 5, r5_, k5_, a5_, b5_, w5_, f5_)
    SBODY(tb + 6, r6_, k6_, a6_, b6_, w6_, f6_)
    SBODY(tb + 7, r7_, k7_, a7_, b7_, w7_, f7_)
  }
#undef SBODY
#undef SLOAD

  *(float4*)(snew + (((size_t)bh * 64 + v) * 64 + ks)) = *(const float4*)&S[0];
  __syncthreads();
  // dump y: one lane per t, 16B per store.
#pragma unroll 4
  for (int it = 0; it < 16; ++it) {
    const int t = lane + it * 64;
    *(float4*)(yout + off_bh + (size_t)t * 2048 + rq * 4) =
        *(const float4*)&ylds[t][0];
  }
}

// ---------------------- GroupNorm + resid + gate ---------------------------

__global__ __launch_bounds__(256)
void k_gn(const float* __restrict__ y, const unsigned short* __restrict__ r,
          const unsigned short* __restrict__ kh, const unsigned short* __restrict__ vf,
          const unsigned short* __restrict__ g, const float* __restrict__ rk,
          const float* __restrict__ lw, const float* __restrict__ lb,
          unsigned short* __restrict__ ywg) {
  const int m = blockIdx.x, tid = threadIdx.x;
  const size_t base = (size_t)m * 2048 + tid * 8;
  float yv[8];
  *(float4*)&yv[0] = *(const float4*)(y + base);
  *(float4*)&yv[4] = *(const float4*)(y + base + 4);
  us8 r8 = *(const us8*)(r + base);
  us8 k8 = *(const us8*)(kh + base);
  us8 v8 = *(const us8*)(vf + base);
  us8 g8 = *(const us8*)(g + base);
  float rkv[8];
  *(float4*)&rkv[0] = *(const float4*)(rk + tid * 8);
  *(float4*)&rkv[4] = *(const float4*)(rk + tid * 8 + 4);
  float sy = 0.f, sd = 0.f;
#pragma unroll
  for (int i = 0; i < 8; ++i) {
    sy += yv[i];
    sd += b2f(r8[i]) * b2f(k8[i]) * rkv[i];
  }
  sy = red8(sy);
  sd = red8(sd);
  const float mu = sy * (1.f / 64.f);
  float sq = 0.f;
#pragma unroll
  for (int i = 0; i < 8; ++i) { const float d = yv[i] - mu; sq += d * d; }
  sq = red8(sq);
  const float rstd = rsqrtf(sq * (1.f / 64.f) + 64e-5f);
  us8 o8;
#pragma unroll
  for (int i = 0; i < 8; ++i) {
    const int c = tid * 8 + i;
    const float gn = (yv[i] - mu) * rstd * lw[c] + lb[c];
    o8[i] = f2b((gn + sd * b2f(v8[i])) * b2f(g8[i]));
  }
  *(us8*)(ywg + base) = o8;
}

// ------------------------------ launch -------------------------------------

extern "C" void kernel_launch(void* const* d_in, const int* in_sizes, int n_in,
                              void* d_out, int out_size, void* d_ws,
                              size_t ws_size, hipStream_t stream) {
  (void)in_sizes; (void)n_in; (void)out_size; (void)ws_size;
  const float* x         = (const float*)d_in[0];
  const float* v_first   = (const float*)d_in[1];
  const float* att_shift = (const float*)d_in[2];
  const float* ffn_shift = (const float*)d_in[3];
  const float* wkv0      = (const float*)d_in[4];
  const float* ln1w = (const float*)d_in[5];
  const float* ln1b = (const float*)d_in[6];
  const float* ln2w = (const float*)d_in[7];
  const float* ln2b = (const float*)d_in[8];
  const float* x_r = (const float*)d_in[9];
  const float* x_w = (const float*)d_in[10];
  const float* x_k = (const float*)d_in[11];
  const float* x_v = (const float*)d_in[12];
  const float* x_a = (const float*)d_in[13];
  const float* x_g = (const float*)d_in[14];
  const float* Wr = (const float*)d_in[15];
  const float* Wk = (const float*)d_in[16];
  const float* Wv = (const float*)d_in[17];
  const float* Wo = (const float*)d_in[18];
  const float* w0 = (const float*)d_in[19];
  const float* w1 = (const float*)d_in[20];
  const float* w2 = (const float*)d_in[21];
  const float* v0 = (const float*)d_in[22];
  const float* v1 = (const float*)d_in[23];
  const float* v2 = (const float*)d_in[24];
  const float* a0 = (const float*)d_in[25];
  const float* a1 = (const float*)d_in[26];
  const float* a2 = (const float*)d_in[27];
  const float* g1 = (const float*)d_in[28];
  const float* g2 = (const float*)d_in[29];
  const float* k_k = (const float*)d_in[30];
  const float* k_a = (const float*)d_in[31];
  const float* r_k = (const float*)d_in[32];
  const float* lnxw = (const float*)d_in[33];
  const float* lnxb = (const float*)d_in[34];
  const float* ffn_xk = (const float*)d_in[35];
  const float* Wkf = (const float*)d_in[36];
  const float* Wvf = (const float*)d_in[37];

  char* ws = (char*)d_ws;
  // ---- arena (total ~166.4 MiB) ----
  constexpr size_t OFF_TWR   = 0;          // 8 MiB each, [N][K] bf16
  constexpr size_t OFF_TWK   = 8388608;
  constexpr size_t OFF_TWV   = 16777216;
  constexpr size_t OFF_TWO   = 25165824;
  constexpr size_t OFF_TW2   = 33554432;   // [2048][64]
  constexpr size_t OFF_TA2   = 33816576;   // [2048][64]
  constexpr size_t OFF_TV2   = 34078720;   // [2048][32]
  constexpr size_t OFF_TG2   = 34209792;   // [2048][128]
  constexpr size_t OFF_TWCAT = 34734080;   // [384][4096]
  constexpr size_t OFF_HACT  = 37879808;   // [4096][288] bf16
  constexpr size_t OFF_GBUF  = 40239104;   // 16 MiB: g bf16 | tWvf half
  constexpr size_t OFF_WH    = 57016320;   // 32 MiB f32: act2 -> wh -> ywg -> kf
  constexpr size_t OFF_R     = 90570752;   // 16 MiB bf16; x1 spans R+KH
  constexpr size_t OFF_KH    = 107347968;  // k raw -> kh
  constexpr size_t OFF_VF    = 124125184;  // bxv -> vf -> xkf
  constexpr size_t OFF_AA    = 140902400;  // bxr -> vraw -> aa ; tWkf spans AA+BB
  constexpr size_t OFF_BB    = 157679616;  // bxk -> a -> bb

  unsigned short* tWr = (unsigned short*)(ws + OFF_TWR);
  unsigned short* tWk = (unsigned short*)(ws + OFF_TWK);
  unsigned short* tWv = (unsigned short*)(ws + OFF_TWV);
  unsigned short* tWo = (unsigned short*)(ws + OFF_TWO);
  unsigned short* tw2 = (unsigned short*)(ws + OFF_TW2);
  unsigned short* ta2 = (unsigned short*)(ws + OFF_TA2);
  unsigned short* tv2 = (unsigned short*)(ws + OFF_TV2);
  unsigned short* tg2 = (unsigned short*)(ws + OFF_TG2);
  unsigned short* tWcat = (unsigned short*)(ws + OFF_TWCAT);
  unsigned short* Hact  = (unsigned short*)(ws + OFF_HACT);
  unsigned short* gbuf  = (unsigned short*)(ws + OFF_GBUF);
  unsigned short* tWvfh = (unsigned short*)(ws + OFF_GBUF);   // alias, post-k_gn
  unsigned short* act2  = (unsigned short*)(ws + OFF_WH);     // [4096][4096]
  float*          whb   = (float*)(ws + OFF_WH);              // wh f32
  unsigned short* ywg   = (unsigned short*)(ws + OFF_WH);     // post-scan
  unsigned short* kf    = (unsigned short*)(ws + OFF_WH);     // [4096][4096] ffn half
  unsigned short* bxr   = (unsigned short*)(ws + OFF_AA);
  unsigned short* bxk   = (unsigned short*)(ws + OFF_BB);
  unsigned short* bxv   = (unsigned short*)(ws + OFF_VF);
  unsigned short* rbuf  = (unsigned short*)(ws + OFF_R);
  unsigned short* khb   = (unsigned short*)(ws + OFF_KH);     // raw k then kh
  unsigned short* vfb   = (unsigned short*)(ws + OFF_VF);
  unsigned short* aab   = (unsigned short*)(ws + OFF_AA);
  unsigned short* bbb   = (unsigned short*)(ws + OFF_BB);
  unsigned short* vraw  = (unsigned short*)(ws + OFF_AA);
  unsigned short* abuf  = (unsigned short*)(ws + OFF_BB);
  float*          x1    = (float*)(ws + OFF_R);               // spans R+KH, f32
  unsigned short* xkf   = (unsigned short*)(ws + OFF_VF);
  unsigned short* tWkf  = (unsigned short*)(ws + OFF_AA);     // [8192][2048] spans AA+BB
  float* out = (float*)d_out;
  float* snew = out + 8388608;

  const dim3 tb(32, 8);
  // ---- weight prep (square + small) ----
  k_transpose<<<dim3(64, 64), tb, 0, stream>>>(Wr, tWr, 2048, 2048);
  k_transpose<<<dim3(64, 64), tb, 0, stream>>>(Wk, tWk, 2048, 2048);
  k_transpose<<<dim3(64, 64), tb, 0, stream>>>(Wv, tWv, 2048, 2048);
  k_transpose<<<dim3(64, 64), tb, 0, stream>>>(Wo, tWo, 2048, 2048);
  k_transpose<<<dim3(64, 2), tb, 0, stream>>>(w2, tw2, 64, 2048);
  k_transpose<<<dim3(64, 2), tb, 0, stream>>>(a2, ta2, 64, 2048);
  k_transpose<<<dim3(64, 1), tb, 0, stream>>>(v2, tv2, 32, 2048);
  k_transpose<<<dim3(64, 4), tb, 0, stream>>>(g2, tg2, 128, 2048);
  k_wcat<<<6144, 256, 0, stream>>>(w1, a1, v1, g1, x_w, x_a, x_v, x_g, tWcat);

  // ---- TimeMix front ----
  k_ln1_mix<<<4096, 256, 0, stream>>>(x, att_shift, ln1w, ln1b, x_r, x_k, x_v,
                                      act2, bxr, bxk, bxv);
  gemm_bt<EP_B16><<<dim3(32, 16), 256, 0, stream>>>(
      bxr, 2048, tWr, 2048, 2048, 2048, 2048, nullptr, rbuf, nullptr, nullptr, nullptr);
  gemm_bt<EP_B16><<<dim3(32, 16), 256, 0, stream>>>(
      bxk, 2048, tWk, 2048, 2048, 2048, 2048, nullptr, khb, nullptr, nullptr, nullptr);
  gemm_bt<EP_B16><<<dim3(32, 16), 256, 0, stream>>>(
      bxv, 2048, tWv, 2048, 2048, 2048, 2048, nullptr, vraw, nullptr, nullptr, nullptr);
  gemm_bt<EP_HACT><<<dim3(32, 3), 256, 0, stream>>>(
      act2, 4096, tWcat, 4096, 288, 4096, 288, nullptr, Hact, nullptr, nullptr, nullptr);
  gemm_bt<EP_W><<<dim3(32, 16), 256, 0, stream>>>(
      Hact + 0, 288, tw2, 64, 2048, 64, 2048, whb, nullptr, w0, nullptr, nullptr);
  gemm_bt<EP_AB16><<<dim3(32, 16), 256, 0, stream>>>(
      Hact + 64, 288, ta2, 64, 2048, 64, 2048, nullptr, abuf, a0, nullptr, nullptr);
  gemm_bt<EP_VGB16><<<dim3(32, 16), 256, 0, stream>>>(
      Hact + 128, 288, tv2, 32, 2048, 32, 2048, nullptr, vfb, v0, v_first, vraw);
  gemm_bt<EP_B16><<<dim3(32, 16), 256, 0, stream>>>(
      Hact + 160, 288, tg2, 128, 2048, 128, 2048, nullptr, gbuf, nullptr, nullptr, nullptr);
  k_post<<<4096, 256, 0, stream>>>(khb, abuf, aab, k_k, k_a);

  // ---- WKV scan: y -> out[0:BTC] (temp), S_new -> out tail ----
  k_scan<<<2048, 64, 0, stream>>>(rbuf, khb, vfb, whb, aab, bbb, wkv0, out, snew);
  k_gn<<<4096, 256, 0, stream>>>(out, rbuf, khb, vfb, gbuf, r_k, lnxw, lnxb, ywg);

  // ---- Wo projection (+x) -> x1 ----
  gemm_bt<EP_ADDF><<<dim3(32, 16), 256, 0, stream>>>(
      ywg, 2048, tWo, 2048, 2048, 2048, 2048, x1, nullptr, nullptr, x, nullptr);

  // ---- ChannelMix (FFN split in two DFF halves to bound workspace) ----
  k_ln2_mix<<<4096, 256, 0, stream>>>(x1, ffn_shift, ln2w, ln2b, ffn_xk, xkf);
  k_transpose<<<dim3(256, 64), tb, 0, stream>>>(Wkf, tWkf, 2048, 8192);
  // half 1: hidden [0,4096)
  gemm_bt<EP_RELU2><<<dim3(32, 32), 256, 0, stream>>>(
      xkf, 2048, tWkf, 2048, 4096, 2048, 4096, nullptr, kf, nullptr, nullptr, nullptr);
  k_transpose<<<dim3(64, 128), tb, 0, stream>>>(Wvf, tWvfh, 4096, 2048);
  gemm_bt<EP_ADDF><<<dim3(32, 16), 256, 0, stream>>>(
      kf, 4096, tWvfh, 4096, 2048, 4096, 2048, out, nullptr, nullptr, x1, nullptr);
  // half 2: hidden [4096,8192)
  gemm_bt<EP_RELU2><<<dim3(32, 32), 256, 0, stream>>>(
      xkf, 2048, tWkf + (size_t)4096 * 2048, 2048, 4096, 2048, 4096, nullptr, kf,
      nullptr, nullptr, nullptr);
  k_transpose<<<dim3(64, 128), tb, 0, stream>>>(Wvf + (size_t)4096 * 2048, tWvfh,
                                                4096, 2048);
  gemm_bt<EP_ADDF><<<dim3(32, 16), 256, 0, stream>>>(
      kf, 4096, tWvfh, 4096, 2048, 4096, 2048, out, nullptr, nullptr, out, nullptr);
}

// Round 6
// 1354.781 us; speedup vs baseline: 1.0450x; 1.0450x over previous
//
#include <hip/hip_runtime.h>
#include <cstdint>

// ---------------------------------------------------------------------------
// RWKV7 block (B=4,T=1024,C=2048,H=32,N=64,DFF=8192) for MI355X gfx950.
// R6: WKV scan staged via global_load_lds ring (depth-8, counted vmcnt(7)),
//     un-sinkable by the compiler; y kept as bf16 in LDS; k_gn reads bf16 y.
// ---------------------------------------------------------------------------

typedef __attribute__((ext_vector_type(4))) float f32x4;
typedef __attribute__((ext_vector_type(8))) __bf16 bf16x8;
typedef __attribute__((ext_vector_type(8))) unsigned short us8;

#define DEV __device__ __forceinline__

DEV unsigned short f2b(float f) {
  union { float f; unsigned u; } v; v.f = f;
  unsigned r = v.u + 0x7fffu + ((v.u >> 16) & 1u);
  return (unsigned short)(r >> 16);
}
DEV float b2f(unsigned short u) {
  union { unsigned u; float f; } v; v.u = (unsigned)u << 16;
  return v.f;
}

DEV void gload16(const void* g, void* l) {
  void* gg = const_cast<void*>(g);
  __builtin_amdgcn_global_load_lds(
      (__attribute__((address_space(1))) unsigned int*)gg,
      (__attribute__((address_space(3))) unsigned int*)l, 16, 0, 0);
}

DEV float red8(float v) {  // sum over aligned 8-lane group
  v += __shfl_xor(v, 1);
  v += __shfl_xor(v, 2);
  v += __shfl_xor(v, 4);
  return v;
}

// ------------------------------ weight prep --------------------------------

__global__ void k_transpose(const float* __restrict__ src,
                            unsigned short* __restrict__ dst, int R, int Cc) {
  __shared__ float tile[32][33];
  const int c0 = blockIdx.x * 32, r0 = blockIdx.y * 32;
  const int tx = threadIdx.x, ty = threadIdx.y;  // block (32,8)
  for (int i = ty; i < 32; i += 8)
    tile[i][tx] = src[(size_t)(r0 + i) * Cc + c0 + tx];
  __syncthreads();
  for (int i = ty; i < 32; i += 8)
    dst[(size_t)(c0 + i) * R + r0 + tx] = f2b(tile[tx][i]);
}

// Wcat^T [384][4096]: rows j: [w1|a1|v1|g1] col j; cols c: c<2048 -> W[c][j],
// c>=2048 -> mix[c-2048]*W[c-2048][j]. Rows 288..383 zero-padded.
__global__ void k_wcat(const float* __restrict__ w1, const float* __restrict__ a1,
                       const float* __restrict__ v1, const float* __restrict__ g1,
                       const float* __restrict__ xw, const float* __restrict__ xa,
                       const float* __restrict__ xv, const float* __restrict__ xg,
                       unsigned short* __restrict__ dst) {
  const int i = blockIdx.x * 256 + threadIdx.x;
  if (i >= 384 * 4096) return;
  const int j = i >> 12, c = i & 4095;
  float val = 0.f;
  if (j < 288) {
    const float* W; const float* mix; int jj, D;
    if (j < 64)       { W = w1; mix = xw; jj = j;       D = 64;  }
    else if (j < 128) { W = a1; mix = xa; jj = j - 64;  D = 64;  }
    else if (j < 160) { W = v1; mix = xv; jj = j - 128; D = 32;  }
    else              { W = g1; mix = xg; jj = j - 160; D = 128; }
    const int cc = c & 2047;
    val = W[(size_t)cc * D + jj];
    if (c >= 2048) val *= mix[cc];
  }
  dst[i] = f2b(val);
}

// ------------------------------ LN + mix -----------------------------------

DEV void breduce2(float& a, float& b, float* rbuf) {
#pragma unroll
  for (int m = 1; m < 64; m <<= 1) { a += __shfl_xor(a, m); b += __shfl_xor(b, m); }
  const int wid = threadIdx.x >> 6, lane = threadIdx.x & 63;
  if (lane == 0) { rbuf[wid] = a; rbuf[4 + wid] = b; }
  __syncthreads();
  a = rbuf[0] + rbuf[1] + rbuf[2] + rbuf[3];
  b = rbuf[4] + rbuf[5] + rbuf[6] + rbuf[7];
  __syncthreads();
}

__global__ __launch_bounds__(256)
void k_ln1_mix(const float* __restrict__ x, const float* __restrict__ shift,
               const float* __restrict__ lw, const float* __restrict__ lb,
               const float* __restrict__ mr, const float* __restrict__ mk,
               const float* __restrict__ mv,
               unsigned short* __restrict__ A2, unsigned short* __restrict__ xrb,
               unsigned short* __restrict__ xkb, unsigned short* __restrict__ xvb) {
  __shared__ float rbuf[8];
  const int m = blockIdx.x, tid = threadIdx.x;
  const int b = m >> 10, t = m & 1023;
  const float* xt = x + (size_t)m * 2048 + tid * 8;
  const float* xp = (t > 0) ? (x + (size_t)(m - 1) * 2048 + tid * 8)
                            : (shift + (size_t)b * 2048 + tid * 8);
  float vt[8], vp[8];
  *(float4*)&vt[0] = *(const float4*)(xt);
  *(float4*)&vt[4] = *(const float4*)(xt + 4);
  *(float4*)&vp[0] = *(const float4*)(xp);
  *(float4*)&vp[4] = *(const float4*)(xp + 4);
  float st = 0.f, sp = 0.f;
#pragma unroll
  for (int i = 0; i < 8; ++i) { st += vt[i]; sp += vp[i]; }
  breduce2(st, sp, rbuf);
  const float mt_ = st * (1.f / 2048.f), mp_ = sp * (1.f / 2048.f);
  float qt = 0.f, qp = 0.f;
#pragma unroll
  for (int i = 0; i < 8; ++i) {
    float d0 = vt[i] - mt_; qt += d0 * d0;
    float d1 = vp[i] - mp_; qp += d1 * d1;
  }
  breduce2(qt, qp, rbuf);
  const float rt = rsqrtf(qt * (1.f / 2048.f) + 1e-5f);
  const float rp = rsqrtf(qp * (1.f / 2048.f) + 1e-5f);
  const bool lnp = (t > 0);
#pragma unroll
  for (int i = 0; i < 8; ++i) {
    const int c = tid * 8 + i;
    const float wv = lw[c], bv = lb[c];
    const float xn = (vt[i] - mt_) * rt * wv + bv;
    const float pn = lnp ? ((vp[i] - mp_) * rp * wv + bv) : vp[i];
    const float xx = pn - xn;
    A2[(size_t)m * 4096 + c] = f2b(xn);
    A2[(size_t)m * 4096 + 2048 + c] = f2b(xx);
    xrb[(size_t)m * 2048 + c] = f2b(xn + xx * mr[c]);
    xkb[(size_t)m * 2048 + c] = f2b(xn + xx * mk[c]);
    xvb[(size_t)m * 2048 + c] = f2b(xn + xx * mv[c]);
  }
}

__global__ __launch_bounds__(256)
void k_ln2_mix(const float* __restrict__ x1, const float* __restrict__ shift,
               const float* __restrict__ lw, const float* __restrict__ lb,
               const float* __restrict__ mk, unsigned short* __restrict__ xkf) {
  __shared__ float rbuf[8];
  const int m = blockIdx.x, tid = threadIdx.x;
  const int b = m >> 10, t = m & 1023;
  const float* xt = x1 + (size_t)m * 2048 + tid * 8;
  const float* xp = (t > 0) ? (x1 + (size_t)(m - 1) * 2048 + tid * 8)
                            : (shift + (size_t)b * 2048 + tid * 8);
  float vt[8], vp[8];
  *(float4*)&vt[0] = *(const float4*)(xt);
  *(float4*)&vt[4] = *(const float4*)(xt + 4);
  *(float4*)&vp[0] = *(const float4*)(xp);
  *(float4*)&vp[4] = *(const float4*)(xp + 4);
  float st = 0.f, sp = 0.f;
#pragma unroll
  for (int i = 0; i < 8; ++i) { st += vt[i]; sp += vp[i]; }
  breduce2(st, sp, rbuf);
  const float mt_ = st * (1.f / 2048.f), mp_ = sp * (1.f / 2048.f);
  float qt = 0.f, qp = 0.f;
#pragma unroll
  for (int i = 0; i < 8; ++i) {
    float d0 = vt[i] - mt_; qt += d0 * d0;
    float d1 = vp[i] - mp_; qp += d1 * d1;
  }
  breduce2(qt, qp, rbuf);
  const float rt = rsqrtf(qt * (1.f / 2048.f) + 1e-5f);
  const float rp = rsqrtf(qp * (1.f / 2048.f) + 1e-5f);
  const bool lnp = (t > 0);
#pragma unroll
  for (int i = 0; i < 8; ++i) {
    const int c = tid * 8 + i;
    const float wv = lw[c], bv = lb[c];
    const float xn = (vt[i] - mt_) * rt * wv + bv;
    const float pn = lnp ? ((vp[i] - mp_) * rp * wv + bv) : vp[i];
    xkf[(size_t)m * 2048 + c] = f2b(xn + (pn - xn) * mk[c]);
  }
}

// ------------------------------ GEMM (bf16 MFMA) ---------------------------
// C[M,N] = A[M,K] @ B[K,N], A bf16 row-major (lda), Bt = B^T bf16 [N][K] (ldb).
// 128x128 tile, BK=32, 256 thr = 4 waves 2x2, each wave 64x64 (4x4 mfma).

constexpr int EP_F32 = 0, EP_B16 = 1, EP_W = 2, EP_AB16 = 3, EP_VGB16 = 4,
              EP_RELU2 = 5, EP_ADDF = 6, EP_HACT = 7;

template <int EP>
DEV void ep_store(float acc, long row, long c, long ldc, float* Co,
                  unsigned short* Cob, const float* bias, const float* e0f,
                  const unsigned short* e0b) {
  const long idx = row * ldc + c;
  if constexpr (EP == EP_F32) {
    Co[idx] = acc;
  } else if constexpr (EP == EP_B16) {
    Cob[idx] = f2b(acc);
  } else if constexpr (EP == EP_W) {
    const float wv = bias[c] + acc;
    const float sp = log1pf(expf(-wv));        // softplus(-wv)
    const float w = -sp - 0.5f;
    Co[idx] = expf(-expf(w));                  // decay in (0,1), f32
  } else if constexpr (EP == EP_AB16) {
    Cob[idx] = f2b(1.f / (1.f + expf(-(bias[c] + acc))));
  } else if constexpr (EP == EP_VGB16) {
    const float s = 1.f / (1.f + expf(-(bias[c] + acc)));
    const float vv = b2f(e0b[idx]);
    Cob[idx] = f2b(vv + (e0f[idx] - vv) * s);
  } else if constexpr (EP == EP_RELU2) {
    const float r = fmaxf(acc, 0.f);
    Cob[idx] = f2b(r * r);
  } else if constexpr (EP == EP_ADDF) {
    Co[idx] = acc + e0f[idx];
  } else if constexpr (EP == EP_HACT) {
    float vv = acc;
    if (c < 64) vv = tanhf(vv);                      // w path
    else if (c >= 160) vv = 1.f / (1.f + expf(-vv)); // g path
    Cob[idx] = f2b(vv);
  }
}

template <int EP>
__global__ __launch_bounds__(256)
void gemm_bt(const unsigned short* __restrict__ A, long lda,
             const unsigned short* __restrict__ Bt, long ldb, long N, long K,
             long ldc, float* __restrict__ Co, unsigned short* __restrict__ Cob,
             const float* __restrict__ bias, const float* __restrict__ e0f,
             const unsigned short* __restrict__ e0b) {
  __shared__ unsigned short As[4096];  // [128][32]
  __shared__ unsigned short Bs[4096];  // [128][32]
  const int tid = threadIdx.x;
  const int wid = tid >> 6, lane = tid & 63;
  const long row0 = (long)blockIdx.x * 128, col0 = (long)blockIdx.y * 128;
  const int wm = (wid >> 1) * 64, wn = (wid & 1) * 64;
  f32x4 acc[4][4] = {};
  const int sr = tid >> 2, sk = (tid & 3) * 8;
  const unsigned short* gA = A + (row0 + sr) * lda + sk;
  const unsigned short* gB = Bt + (col0 + sr) * ldb + sk;
  unsigned short* lA = As + wid * 512;
  unsigned short* lB = Bs + wid * 512;
  const int fr = lane & 15, fk = (lane >> 4) * 8;

  for (long kb = 0; kb < K; kb += 32) {
    gload16(gA + kb, lA);
    gload16(gA + kb + 64 * lda, lA + 2048);
    gload16(gB + kb, lB);
    gload16(gB + kb + 64 * ldb, lB + 2048);
    __syncthreads();  // drains vmcnt before barrier (m97 structure)
    bf16x8 af[4], bq[4];
#pragma unroll
    for (int mt = 0; mt < 4; ++mt)
      af[mt] = *(const bf16x8*)(As + (wm + mt * 16 + fr) * 32 + fk);
#pragma unroll
    for (int nt = 0; nt < 4; ++nt)
      bq[nt] = *(const bf16x8*)(Bs + (wn + nt * 16 + fr) * 32 + fk);
#pragma unroll
    for (int mt = 0; mt < 4; ++mt)
#pragma unroll
      for (int nt = 0; nt < 4; ++nt)
        acc[mt][nt] = __builtin_amdgcn_mfma_f32_16x16x32_bf16(
            af[mt], bq[nt], acc[mt][nt], 0, 0, 0);
    __syncthreads();
  }
  const int fq = lane >> 4;
#pragma unroll
  for (int mt = 0; mt < 4; ++mt) {
#pragma unroll
    for (int nt = 0; nt < 4; ++nt) {
      const long c = col0 + wn + nt * 16 + fr;
      if (c < N) {
        const long rb = row0 + wm + mt * 16 + fq * 4;
#pragma unroll
        for (int rg = 0; rg < 4; ++rg)
          ep_store<EP>(acc[mt][nt][rg], rb + rg, c, ldc, Co, Cob, bias, e0f, e0b);
      }
    }
  }
}

// ------------------------------ k_post -------------------------------------
// kk normalize: kio(raw k)->kh in place; abio(a)->bb in place; aao <- -kk.
__global__ __launch_bounds__(256)
void k_post(unsigned short* __restrict__ kio, unsigned short* __restrict__ abio,
            unsigned short* __restrict__ aao, const float* __restrict__ kkw,
            const float* __restrict__ kaw) {
  const int m = blockIdx.x, tid = threadIdx.x;
  const size_t base = (size_t)m * 2048 + tid * 8;
  us8 k8 = *(const us8*)(kio + base);
  us8 a8 = *(const us8*)(abio + base);
  float kk8[8], ka8[8];
  *(float4*)&kk8[0] = *(const float4*)(kkw + tid * 8);
  *(float4*)&kk8[4] = *(const float4*)(kkw + tid * 8 + 4);
  *(float4*)&ka8[0] = *(const float4*)(kaw + tid * 8);
  *(float4*)&ka8[4] = *(const float4*)(kaw + tid * 8 + 4);
  float kx[8], kv[8], av[8];
  float ss = 0.f;
#pragma unroll
  for (int i = 0; i < 8; ++i) {
    kv[i] = b2f(k8[i]); av[i] = b2f(a8[i]);
    kx[i] = kv[i] * kk8[i]; ss += kx[i] * kx[i];
  }
  ss = red8(ss);  // per-head (64 ch = 8 lanes)
  const float inv = 1.f / fmaxf(sqrtf(ss), 1e-12f);
  us8 kh8, aa8, bb8;
#pragma unroll
  for (int i = 0; i < 8; ++i) {
    const float kkn = kx[i] * inv;
    kh8[i] = f2b(kv[i] * (1.f + (av[i] - 1.f) * ka8[i]));
    aa8[i] = f2b(-kkn);
    bb8[i] = f2b(kkn * av[i]);
  }
  *(us8*)(kio + base) = kh8;
  *(us8*)(aao + base) = aa8;
  *(us8*)(abio + base) = bb8;
}

// ------------------------------ WKV scan -----------------------------------
// 2048 blocks x 64 threads (1 wave). block = (bh, rq): 4 value-rows.
// lane = rl*16 + kg; kg (0..15) owns 4 k's, rl (0..3) one row.
// Staging: global_load_lds ring, 8 slots x 784B; 49 lanes issue ONE gload16
// per step -> vmcnt +1/step; wait vmcnt(7) = depth-8 pipeline the compiler
// cannot sink (asm-pinned). Slot layout (bytes):
//   r[0,128) k[128,256) a[256,384) b[384,512) bf16; w[512,768) f32; vf[768,784).
// 16-lane k-reduction in pure DPP. y stored bf16 in LDS, bulk-dumped at end.

DEV float red16(float x) {  // all-lanes sum within each 16-lane row
  union { float f; int i; } a, r;
  a.f = x; r.i = __builtin_amdgcn_update_dpp(0, a.i, 0xB1, 0xf, 0xf, true);  // quad xor1
  x += r.f;
  a.f = x; r.i = __builtin_amdgcn_update_dpp(0, a.i, 0x4E, 0xf, 0xf, true);  // quad xor2
  x += r.f;
  a.f = x; r.i = __builtin_amdgcn_update_dpp(0, a.i, 0x124, 0xf, 0xf, true); // row_ror:4
  x += r.f;
  a.f = x; r.i = __builtin_amdgcn_update_dpp(0, a.i, 0x128, 0xf, 0xf, true); // row_ror:8
  x += r.f;
  return x;
}

DEV void cv4(const uint2 q, float* o) {  // 4 bf16 (2 dwords) -> 4 f32
  union { unsigned u; float f; } t;
  t.u = q.x << 16;          o[0] = t.f;
  t.u = q.x & 0xffff0000u;  o[1] = t.f;
  t.u = q.y << 16;          o[2] = t.f;
  t.u = q.y & 0xffff0000u;  o[3] = t.f;
}

__global__ __launch_bounds__(64)
void k_scan(const unsigned short* __restrict__ rp,
            const unsigned short* __restrict__ kp,
            const unsigned short* __restrict__ vp,
            const float* __restrict__ wp,
            const unsigned short* __restrict__ ap,
            const unsigned short* __restrict__ bp,
            const float* __restrict__ s0, unsigned short* __restrict__ yout,
            float* __restrict__ snew) {
  __shared__ float4 slots[8][49];           // 8 x 784B staging ring
  __shared__ unsigned short ylds[1024][4];  // 8 KiB, y as bf16
  const int lane = threadIdx.x;
  const int bh = blockIdx.x & 127;   // siblings bh+128*rq -> same XCD (mod 8)
  const int rq = blockIdx.x >> 7;    // 0..15
  const int b = bh >> 5, h = bh & 31;
  const int kg = lane & 15, rl = lane >> 4;
  const int v = rq * 4 + rl, ks = kg * 4;
  const size_t off_bh = (size_t)b * 1024 * 2048 + (size_t)h * 64;

  float S[4];
  *(float4*)&S[0] = *(const float4*)(s0 + (((size_t)bh * 64 + v) * 64 + ks));

  // per-lane staging source (lane < 49)
  const char* gp = nullptr;
  size_t gstep = 0;
  if (lane < 49) {
    if (lane < 32) {
      const int arr = lane >> 3, sub = lane & 7;
      const unsigned short* base = arr == 0 ? rp : arr == 1 ? kp
                                 : arr == 2 ? ap : bp;
      gp = (const char*)(base + off_bh + sub * 8);
      gstep = 4096;
    } else if (lane < 48) {
      gp = (const char*)(wp + off_bh + (lane - 32) * 4);
      gstep = 8192;
    } else {
      gp = (const char*)(vp + off_bh + (rq & ~1) * 4);
      gstep = 4096;
    }
  }
  // prologue: stage t = 0..7
#pragma unroll
  for (int s = 0; s < 8; ++s) {
    if (lane < 49) gload16(gp, &slots[s][0]);
    gp += gstep;
  }

  for (int t = 0; t < 1024; ++t) {
    asm volatile("s_waitcnt vmcnt(7)" ::: "memory");
    const int sl = t & 7;
    const char* sb = (const char*)&slots[sl][0];
    uint2 r2 = *(const uint2*)(sb + kg * 8);
    uint2 k2 = *(const uint2*)(sb + 128 + kg * 8);
    uint2 a2 = *(const uint2*)(sb + 256 + kg * 8);
    uint2 b2 = *(const uint2*)(sb + 384 + kg * 8);
    float4 wf = *(const float4*)(sb + 512 + kg * 16);
    const unsigned short vfu =
        *(const unsigned short*)(sb + 768 + ((rq & 1) * 4 + rl) * 2);
    asm volatile("s_waitcnt lgkmcnt(0)" ::: "memory");
    if (lane < 49) gload16(gp, &slots[sl][0]);  // stage t+8 (clamped)
    if (t < 1015) gp += gstep;

    float rr[4], kk[4], av[4], bv[4];
    cv4(r2, rr); cv4(k2, kk); cv4(a2, av); cv4(b2, bv);
    const float vv = b2f(vfu);
    float sa = S[0] * av[0] + S[1] * av[1] + S[2] * av[2] + S[3] * av[3];
    sa = red16(sa);
    float y;
    S[0] = S[0] * wf.x + sa * bv[0] + vv * kk[0]; y  = S[0] * rr[0];
    S[1] = S[1] * wf.y + sa * bv[1] + vv * kk[1]; y += S[1] * rr[1];
    S[2] = S[2] * wf.z + sa * bv[2] + vv * kk[2]; y += S[2] * rr[2];
    S[3] = S[3] * wf.w + sa * bv[3] + vv * kk[3]; y += S[3] * rr[3];
    y = red16(y);
    if (kg == 0) ylds[t][rl] = f2b(y);
  }

  *(float4*)(snew + (((size_t)bh * 64 + v) * 64 + ks)) = *(const float4*)&S[0];
  asm volatile("s_waitcnt lgkmcnt(0)" ::: "memory");
  // dump y: one lane per t, 8B per store.
#pragma unroll 4
  for (int it = 0; it < 16; ++it) {
    const int t = lane + it * 64;
    const uint2 val = *(const uint2*)&ylds[t][0];
    *(uint2*)(yout + off_bh + (size_t)t * 2048 + rq * 4) = val;
  }
}

// ---------------------- GroupNorm + resid + gate ---------------------------

__global__ __launch_bounds__(256)
void k_gn(const unsigned short* __restrict__ y, const unsigned short* __restrict__ r,
          const unsigned short* __restrict__ kh, const unsigned short* __restrict__ vf,
          const unsigned short* __restrict__ g, const float* __restrict__ rk,
          const float* __restrict__ lw, const float* __restrict__ lb,
          unsigned short* __restrict__ ywg) {
  const int m = blockIdx.x, tid = threadIdx.x;
  const size_t base = (size_t)m * 2048 + tid * 8;
  us8 y8 = *(const us8*)(y + base);
  us8 r8 = *(const us8*)(r + base);
  us8 k8 = *(const us8*)(kh + base);
  us8 v8 = *(const us8*)(vf + base);
  us8 g8 = *(const us8*)(g + base);
  float yv[8];
  float rkv[8];
  *(float4*)&rkv[0] = *(const float4*)(rk + tid * 8);
  *(float4*)&rkv[4] = *(const float4*)(rk + tid * 8 + 4);
  float sy = 0.f, sd = 0.f;
#pragma unroll
  for (int i = 0; i < 8; ++i) {
    yv[i] = b2f(y8[i]);
    sy += yv[i];
    sd += b2f(r8[i]) * b2f(k8[i]) * rkv[i];
  }
  sy = red8(sy);
  sd = red8(sd);
  const float mu = sy * (1.f / 64.f);
  float sq = 0.f;
#pragma unroll
  for (int i = 0; i < 8; ++i) { const float d = yv[i] - mu; sq += d * d; }
  sq = red8(sq);
  const float rstd = rsqrtf(sq * (1.f / 64.f) + 64e-5f);
  us8 o8;
#pragma unroll
  for (int i = 0; i < 8; ++i) {
    const int c = tid * 8 + i;
    const float gn = (yv[i] - mu) * rstd * lw[c] + lb[c];
    o8[i] = f2b((gn + sd * b2f(v8[i])) * b2f(g8[i]));
  }
  *(us8*)(ywg + base) = o8;
}

// ------------------------------ launch -------------------------------------

extern "C" void kernel_launch(void* const* d_in, const int* in_sizes, int n_in,
                              void* d_out, int out_size, void* d_ws,
                              size_t ws_size, hipStream_t stream) {
  (void)in_sizes; (void)n_in; (void)out_size; (void)ws_size;
  const float* x         = (const float*)d_in[0];
  const float* v_first   = (const float*)d_in[1];
  const float* att_shift = (const float*)d_in[2];
  const float* ffn_shift = (const float*)d_in[3];
  const float* wkv0      = (const float*)d_in[4];
  const float* ln1w = (const float*)d_in[5];
  const float* ln1b = (const float*)d_in[6];
  const float* ln2w = (const float*)d_in[7];
  const float* ln2b = (const float*)d_in[8];
  const float* x_r = (const float*)d_in[9];
  const float* x_w = (const float*)d_in[10];
  const float* x_k = (const float*)d_in[11];
  const float* x_v = (const float*)d_in[12];
  const float* x_a = (const float*)d_in[13];
  const float* x_g = (const float*)d_in[14];
  const float* Wr = (const float*)d_in[15];
  const float* Wk = (const float*)d_in[16];
  const float* Wv = (const float*)d_in[17];
  const float* Wo = (const float*)d_in[18];
  const float* w0 = (const float*)d_in[19];
  const float* w1 = (const float*)d_in[20];
  const float* w2 = (const float*)d_in[21];
  const float* v0 = (const float*)d_in[22];
  const float* v1 = (const float*)d_in[23];
  const float* v2 = (const float*)d_in[24];
  const float* a0 = (const float*)d_in[25];
  const float* a1 = (const float*)d_in[26];
  const float* a2 = (const float*)d_in[27];
  const float* g1 = (const float*)d_in[28];
  const float* g2 = (const float*)d_in[29];
  const float* k_k = (const float*)d_in[30];
  const float* k_a = (const float*)d_in[31];
  const float* r_k = (const float*)d_in[32];
  const float* lnxw = (const float*)d_in[33];
  const float* lnxb = (const float*)d_in[34];
  const float* ffn_xk = (const float*)d_in[35];
  const float* Wkf = (const float*)d_in[36];
  const float* Wvf = (const float*)d_in[37];

  char* ws = (char*)d_ws;
  // ---- arena (total ~166.4 MiB) ----
  constexpr size_t OFF_TWR   = 0;          // 8 MiB each, [N][K] bf16
  constexpr size_t OFF_TWK   = 8388608;
  constexpr size_t OFF_TWV   = 16777216;
  constexpr size_t OFF_TWO   = 25165824;
  constexpr size_t OFF_TW2   = 33554432;   // [2048][64]
  constexpr size_t OFF_TA2   = 33816576;   // [2048][64]
  constexpr size_t OFF_TV2   = 34078720;   // [2048][32]
  constexpr size_t OFF_TG2   = 34209792;   // [2048][128]
  constexpr size_t OFF_TWCAT = 34734080;   // [384][4096]
  constexpr size_t OFF_HACT  = 37879808;   // [4096][288] bf16
  constexpr size_t OFF_GBUF  = 40239104;   // 16 MiB: g bf16 | tWvf half
  constexpr size_t OFF_WH    = 57016320;   // 32 MiB f32: act2 -> wh -> ywg -> kf
  constexpr size_t OFF_R     = 90570752;   // 16 MiB bf16; x1 spans R+KH
  constexpr size_t OFF_KH    = 107347968;  // k raw -> kh
  constexpr size_t OFF_VF    = 124125184;  // bxv -> vf -> xkf
  constexpr size_t OFF_AA    = 140902400;  // bxr -> vraw -> aa ; tWkf spans AA+BB
  constexpr size_t OFF_BB    = 157679616;  // bxk -> a -> bb

  unsigned short* tWr = (unsigned short*)(ws + OFF_TWR);
  unsigned short* tWk = (unsigned short*)(ws + OFF_TWK);
  unsigned short* tWv = (unsigned short*)(ws + OFF_TWV);
  unsigned short* tWo = (unsigned short*)(ws + OFF_TWO);
  unsigned short* tw2 = (unsigned short*)(ws + OFF_TW2);
  unsigned short* ta2 = (unsigned short*)(ws + OFF_TA2);
  unsigned short* tv2 = (unsigned short*)(ws + OFF_TV2);
  unsigned short* tg2 = (unsigned short*)(ws + OFF_TG2);
  unsigned short* tWcat = (unsigned short*)(ws + OFF_TWCAT);
  unsigned short* Hact  = (unsigned short*)(ws + OFF_HACT);
  unsigned short* gbuf  = (unsigned short*)(ws + OFF_GBUF);
  unsigned short* tWvfh = (unsigned short*)(ws + OFF_GBUF);   // alias, post-k_gn
  unsigned short* act2  = (unsigned short*)(ws + OFF_WH);     // [4096][4096]
  float*          whb   = (float*)(ws + OFF_WH);              // wh f32
  unsigned short* ywg   = (unsigned short*)(ws + OFF_WH);     // post-scan
  unsigned short* kf    = (unsigned short*)(ws + OFF_WH);     // [4096][4096] ffn half
  unsigned short* bxr   = (unsigned short*)(ws + OFF_AA);
  unsigned short* bxk   = (unsigned short*)(ws + OFF_BB);
  unsigned short* bxv   = (unsigned short*)(ws + OFF_VF);
  unsigned short* rbuf  = (unsigned short*)(ws + OFF_R);
  unsigned short* khb   = (unsigned short*)(ws + OFF_KH);     // raw k then kh
  unsigned short* vfb   = (unsigned short*)(ws + OFF_VF);
  unsigned short* aab   = (unsigned short*)(ws + OFF_AA);
  unsigned short* bbb   = (unsigned short*)(ws + OFF_BB);
  unsigned short* vraw  = (unsigned short*)(ws + OFF_AA);
  unsigned short* abuf  = (unsigned short*)(ws + OFF_BB);
  float*          x1    = (float*)(ws + OFF_R);               // spans R+KH, f32
  unsigned short* xkf   = (unsigned short*)(ws + OFF_VF);
  unsigned short* tWkf  = (unsigned short*)(ws + OFF_AA);     // [8192][2048] spans AA+BB
  float* out = (float*)d_out;
  float* snew = out + 8388608;

  const dim3 tb(32, 8);
  // ---- weight prep (square + small) ----
  k_transpose<<<dim3(64, 64), tb, 0, stream>>>(Wr, tWr, 2048, 2048);
  k_transpose<<<dim3(64, 64), tb, 0, stream>>>(Wk, tWk, 2048, 2048);
  k_transpose<<<dim3(64, 64), tb, 0, stream>>>(Wv, tWv, 2048, 2048);
  k_transpose<<<dim3(64, 64), tb, 0, stream>>>(Wo, tWo, 2048, 2048);
  k_transpose<<<dim3(64, 2), tb, 0, stream>>>(w2, tw2, 64, 2048);
  k_transpose<<<dim3(64, 2), tb, 0, stream>>>(a2, ta2, 64, 2048);
  k_transpose<<<dim3(64, 1), tb, 0, stream>>>(v2, tv2, 32, 2048);
  k_transpose<<<dim3(64, 4), tb, 0, stream>>>(g2, tg2, 128, 2048);
  k_wcat<<<6144, 256, 0, stream>>>(w1, a1, v1, g1, x_w, x_a, x_v, x_g, tWcat);

  // ---- TimeMix front ----
  k_ln1_mix<<<4096, 256, 0, stream>>>(x, att_shift, ln1w, ln1b, x_r, x_k, x_v,
                                      act2, bxr, bxk, bxv);
  gemm_bt<EP_B16><<<dim3(32, 16), 256, 0, stream>>>(
      bxr, 2048, tWr, 2048, 2048, 2048, 2048, nullptr, rbuf, nullptr, nullptr, nullptr);
  gemm_bt<EP_B16><<<dim3(32, 16), 256, 0, stream>>>(
      bxk, 2048, tWk, 2048, 2048, 2048, 2048, nullptr, khb, nullptr, nullptr, nullptr);
  gemm_bt<EP_B16><<<dim3(32, 16), 256, 0, stream>>>(
      bxv, 2048, tWv, 2048, 2048, 2048, 2048, nullptr, vraw, nullptr, nullptr, nullptr);
  gemm_bt<EP_HACT><<<dim3(32, 3), 256, 0, stream>>>(
      act2, 4096, tWcat, 4096, 288, 4096, 288, nullptr, Hact, nullptr, nullptr, nullptr);
  gemm_bt<EP_W><<<dim3(32, 16), 256, 0, stream>>>(
      Hact + 0, 288, tw2, 64, 2048, 64, 2048, whb, nullptr, w0, nullptr, nullptr);
  gemm_bt<EP_AB16><<<dim3(32, 16), 256, 0, stream>>>(
      Hact + 64, 288, ta2, 64, 2048, 64, 2048, nullptr, abuf, a0, nullptr, nullptr);
  gemm_bt<EP_VGB16><<<dim3(32, 16), 256, 0, stream>>>(
      Hact + 128, 288, tv2, 32, 2048, 32, 2048, nullptr, vfb, v0, v_first, vraw);
  gemm_bt<EP_B16><<<dim3(32, 16), 256, 0, stream>>>(
      Hact + 160, 288, tg2, 128, 2048, 128, 2048, nullptr, gbuf, nullptr, nullptr, nullptr);
  k_post<<<4096, 256, 0, stream>>>(khb, abuf, aab, k_k, k_a);

  // ---- WKV scan: y (bf16) -> out[0:BTC] (temp), S_new -> out tail ----
  k_scan<<<2048, 64, 0, stream>>>(rbuf, khb, vfb, whb, aab, bbb, wkv0,
                                  (unsigned short*)out, snew);
  k_gn<<<4096, 256, 0, stream>>>((const unsigned short*)out, rbuf, khb, vfb,
                                 gbuf, r_k, lnxw, lnxb, ywg);

  // ---- Wo projection (+x) -> x1 ----
  gemm_bt<EP_ADDF><<<dim3(32, 16), 256, 0, stream>>>(
      ywg, 2048, tWo, 2048, 2048, 2048, 2048, x1, nullptr, nullptr, x, nullptr);

  // ---- ChannelMix (FFN split in two DFF halves to bound workspace) ----
  k_ln2_mix<<<4096, 256, 0, stream>>>(x1, ffn_shift, ln2w, ln2b, ffn_xk, xkf);
  k_transpose<<<dim3(256, 64), tb, 0, stream>>>(Wkf, tWkf, 2048, 8192);
  // half 1: hidden [0,4096)
  gemm_bt<EP_RELU2><<<dim3(32, 32), 256, 0, stream>>>(
      xkf, 2048, tWkf, 2048, 4096, 2048, 4096, nullptr, kf, nullptr, nullptr, nullptr);
  k_transpose<<<dim3(64, 128), tb, 0, stream>>>(Wvf, tWvfh, 4096, 2048);
  gemm_bt<EP_ADDF><<<dim3(32, 16), 256, 0, stream>>>(
      kf, 4096, tWvfh, 4096, 2048, 4096, 2048, out, nullptr, nullptr, x1, nullptr);
  // half 2: hidden [4096,8192)
  gemm_bt<EP_RELU2><<<dim3(32, 32), 256, 0, stream>>>(
      xkf, 2048, tWkf + (size_t)4096 * 2048, 2048, 4096, 2048, 4096, nullptr, kf,
      nullptr, nullptr, nullptr);
  k_transpose<<<dim3(64, 128), tb, 0, stream>>>(Wvf + (size_t)4096 * 2048, tWvfh,
                                                4096, 2048);
  gemm_bt<EP_ADDF><<<dim3(32, 16), 256, 0, stream>>>(
      kf, 4096, tWvfh, 4096, 2048, 4096, 2048, out, nullptr, nullptr, out, nullptr);
}

// Round 7
// 1277.234 us; speedup vs baseline: 1.1084x; 1.0607x over previous
//
#include <hip/hip_runtime.h>
#include <cstdint>

// ---------------------------------------------------------------------------
// RWKV7 block (B=4,T=1024,C=2048,H=32,N=64,DFF=8192) for MI355X gfx950.
// R7: new gemm2 (128x256 tile, BK=32, 8 waves, counted-vmcnt double-buffer,
//     XOR-swizzled LDS, setprio) for the 8 big GEMMs. Scan unchanged (R6).
// ---------------------------------------------------------------------------

typedef __attribute__((ext_vector_type(4))) float f32x4;
typedef __attribute__((ext_vector_type(8))) __bf16 bf16x8;
typedef __attribute__((ext_vector_type(8))) unsigned short us8;

#define DEV __device__ __forceinline__

DEV unsigned short f2b(float f) {
  union { float f; unsigned u; } v; v.f = f;
  unsigned r = v.u + 0x7fffu + ((v.u >> 16) & 1u);
  return (unsigned short)(r >> 16);
}
DEV float b2f(unsigned short u) {
  union { unsigned u; float f; } v; v.u = (unsigned)u << 16;
  return v.f;
}

DEV void gload16(const void* g, void* l) {
  void* gg = const_cast<void*>(g);
  __builtin_amdgcn_global_load_lds(
      (__attribute__((address_space(1))) unsigned int*)gg,
      (__attribute__((address_space(3))) unsigned int*)l, 16, 0, 0);
}

DEV float red8(float v) {  // sum over aligned 8-lane group
  v += __shfl_xor(v, 1);
  v += __shfl_xor(v, 2);
  v += __shfl_xor(v, 4);
  return v;
}

// ------------------------------ weight prep --------------------------------

__global__ void k_transpose(const float* __restrict__ src,
                            unsigned short* __restrict__ dst, int R, int Cc) {
  __shared__ float tile[32][33];
  const int c0 = blockIdx.x * 32, r0 = blockIdx.y * 32;
  const int tx = threadIdx.x, ty = threadIdx.y;  // block (32,8)
  for (int i = ty; i < 32; i += 8)
    tile[i][tx] = src[(size_t)(r0 + i) * Cc + c0 + tx];
  __syncthreads();
  for (int i = ty; i < 32; i += 8)
    dst[(size_t)(c0 + i) * R + r0 + tx] = f2b(tile[tx][i]);
}

// Wcat^T [384][4096]
__global__ void k_wcat(const float* __restrict__ w1, const float* __restrict__ a1,
                       const float* __restrict__ v1, const float* __restrict__ g1,
                       const float* __restrict__ xw, const float* __restrict__ xa,
                       const float* __restrict__ xv, const float* __restrict__ xg,
                       unsigned short* __restrict__ dst) {
  const int i = blockIdx.x * 256 + threadIdx.x;
  if (i >= 384 * 4096) return;
  const int j = i >> 12, c = i & 4095;
  float val = 0.f;
  if (j < 288) {
    const float* W; const float* mix; int jj, D;
    if (j < 64)       { W = w1; mix = xw; jj = j;       D = 64;  }
    else if (j < 128) { W = a1; mix = xa; jj = j - 64;  D = 64;  }
    else if (j < 160) { W = v1; mix = xv; jj = j - 128; D = 32;  }
    else              { W = g1; mix = xg; jj = j - 160; D = 128; }
    const int cc = c & 2047;
    val = W[(size_t)cc * D + jj];
    if (c >= 2048) val *= mix[cc];
  }
  dst[i] = f2b(val);
}

// ------------------------------ LN + mix -----------------------------------

DEV void breduce2(float& a, float& b, float* rbuf) {
#pragma unroll
  for (int m = 1; m < 64; m <<= 1) { a += __shfl_xor(a, m); b += __shfl_xor(b, m); }
  const int wid = threadIdx.x >> 6, lane = threadIdx.x & 63;
  if (lane == 0) { rbuf[wid] = a; rbuf[4 + wid] = b; }
  __syncthreads();
  a = rbuf[0] + rbuf[1] + rbuf[2] + rbuf[3];
  b = rbuf[4] + rbuf[5] + rbuf[6] + rbuf[7];
  __syncthreads();
}

__global__ __launch_bounds__(256)
void k_ln1_mix(const float* __restrict__ x, const float* __restrict__ shift,
               const float* __restrict__ lw, const float* __restrict__ lb,
               const float* __restrict__ mr, const float* __restrict__ mk,
               const float* __restrict__ mv,
               unsigned short* __restrict__ A2, unsigned short* __restrict__ xrb,
               unsigned short* __restrict__ xkb, unsigned short* __restrict__ xvb) {
  __shared__ float rbuf[8];
  const int m = blockIdx.x, tid = threadIdx.x;
  const int b = m >> 10, t = m & 1023;
  const float* xt = x + (size_t)m * 2048 + tid * 8;
  const float* xp = (t > 0) ? (x + (size_t)(m - 1) * 2048 + tid * 8)
                            : (shift + (size_t)b * 2048 + tid * 8);
  float vt[8], vp[8];
  *(float4*)&vt[0] = *(const float4*)(xt);
  *(float4*)&vt[4] = *(const float4*)(xt + 4);
  *(float4*)&vp[0] = *(const float4*)(xp);
  *(float4*)&vp[4] = *(const float4*)(xp + 4);
  float st = 0.f, sp = 0.f;
#pragma unroll
  for (int i = 0; i < 8; ++i) { st += vt[i]; sp += vp[i]; }
  breduce2(st, sp, rbuf);
  const float mt_ = st * (1.f / 2048.f), mp_ = sp * (1.f / 2048.f);
  float qt = 0.f, qp = 0.f;
#pragma unroll
  for (int i = 0; i < 8; ++i) {
    float d0 = vt[i] - mt_; qt += d0 * d0;
    float d1 = vp[i] - mp_; qp += d1 * d1;
  }
  breduce2(qt, qp, rbuf);
  const float rt = rsqrtf(qt * (1.f / 2048.f) + 1e-5f);
  const float rp = rsqrtf(qp * (1.f / 2048.f) + 1e-5f);
  const bool lnp = (t > 0);
#pragma unroll
  for (int i = 0; i < 8; ++i) {
    const int c = tid * 8 + i;
    const float wv = lw[c], bv = lb[c];
    const float xn = (vt[i] - mt_) * rt * wv + bv;
    const float pn = lnp ? ((vp[i] - mp_) * rp * wv + bv) : vp[i];
    const float xx = pn - xn;
    A2[(size_t)m * 4096 + c] = f2b(xn);
    A2[(size_t)m * 4096 + 2048 + c] = f2b(xx);
    xrb[(size_t)m * 2048 + c] = f2b(xn + xx * mr[c]);
    xkb[(size_t)m * 2048 + c] = f2b(xn + xx * mk[c]);
    xvb[(size_t)m * 2048 + c] = f2b(xn + xx * mv[c]);
  }
}

__global__ __launch_bounds__(256)
void k_ln2_mix(const float* __restrict__ x1, const float* __restrict__ shift,
               const float* __restrict__ lw, const float* __restrict__ lb,
               const float* __restrict__ mk, unsigned short* __restrict__ xkf) {
  __shared__ float rbuf[8];
  const int m = blockIdx.x, tid = threadIdx.x;
  const int b = m >> 10, t = m & 1023;
  const float* xt = x1 + (size_t)m * 2048 + tid * 8;
  const float* xp = (t > 0) ? (x1 + (size_t)(m - 1) * 2048 + tid * 8)
                            : (shift + (size_t)b * 2048 + tid * 8);
  float vt[8], vp[8];
  *(float4*)&vt[0] = *(const float4*)(xt);
  *(float4*)&vt[4] = *(const float4*)(xt + 4);
  *(float4*)&vp[0] = *(const float4*)(xp);
  *(float4*)&vp[4] = *(const float4*)(xp + 4);
  float st = 0.f, sp = 0.f;
#pragma unroll
  for (int i = 0; i < 8; ++i) { st += vt[i]; sp += vp[i]; }
  breduce2(st, sp, rbuf);
  const float mt_ = st * (1.f / 2048.f), mp_ = sp * (1.f / 2048.f);
  float qt = 0.f, qp = 0.f;
#pragma unroll
  for (int i = 0; i < 8; ++i) {
    float d0 = vt[i] - mt_; qt += d0 * d0;
    float d1 = vp[i] - mp_; qp += d1 * d1;
  }
  breduce2(qt, qp, rbuf);
  const float rt = rsqrtf(qt * (1.f / 2048.f) + 1e-5f);
  const float rp = rsqrtf(qp * (1.f / 2048.f) + 1e-5f);
  const bool lnp = (t > 0);
#pragma unroll
  for (int i = 0; i < 8; ++i) {
    const int c = tid * 8 + i;
    const float wv = lw[c], bv = lb[c];
    const float xn = (vt[i] - mt_) * rt * wv + bv;
    const float pn = lnp ? ((vp[i] - mp_) * rp * wv + bv) : vp[i];
    xkf[(size_t)m * 2048 + c] = f2b(xn + (pn - xn) * mk[c]);
  }
}

// ------------------------------ epilogues ----------------------------------

constexpr int EP_F32 = 0, EP_B16 = 1, EP_W = 2, EP_AB16 = 3, EP_VGB16 = 4,
              EP_RELU2 = 5, EP_ADDF = 6, EP_HACT = 7;

template <int EP>
DEV void ep_store(float acc, long row, long c, long ldc, float* Co,
                  unsigned short* Cob, const float* bias, const float* e0f,
                  const unsigned short* e0b) {
  const long idx = row * ldc + c;
  if constexpr (EP == EP_F32) {
    Co[idx] = acc;
  } else if constexpr (EP == EP_B16) {
    Cob[idx] = f2b(acc);
  } else if constexpr (EP == EP_W) {
    const float wv = bias[c] + acc;
    const float sp = log1pf(expf(-wv));        // softplus(-wv)
    const float w = -sp - 0.5f;
    Co[idx] = expf(-expf(w));                  // decay in (0,1), f32
  } else if constexpr (EP == EP_AB16) {
    Cob[idx] = f2b(1.f / (1.f + expf(-(bias[c] + acc))));
  } else if constexpr (EP == EP_VGB16) {
    const float s = 1.f / (1.f + expf(-(bias[c] + acc)));
    const float vv = b2f(e0b[idx]);
    Cob[idx] = f2b(vv + (e0f[idx] - vv) * s);
  } else if constexpr (EP == EP_RELU2) {
    const float r = fmaxf(acc, 0.f);
    Cob[idx] = f2b(r * r);
  } else if constexpr (EP == EP_ADDF) {
    Co[idx] = acc + e0f[idx];
  } else if constexpr (EP == EP_HACT) {
    float vv = acc;
    if (c < 64) vv = tanhf(vv);                      // w path
    else if (c >= 160) vv = 1.f / (1.f + expf(-vv)); // g path
    Cob[idx] = f2b(vv);
  }
}

// ---------------- GEMM v1 (128x128, small/odd shapes) ----------------------

template <int EP>
__global__ __launch_bounds__(256)
void gemm_bt(const unsigned short* __restrict__ A, long lda,
             const unsigned short* __restrict__ Bt, long ldb, long N, long K,
             long ldc, float* __restrict__ Co, unsigned short* __restrict__ Cob,
             const float* __restrict__ bias, const float* __restrict__ e0f,
             const unsigned short* __restrict__ e0b) {
  __shared__ unsigned short As[4096];  // [128][32]
  __shared__ unsigned short Bs[4096];  // [128][32]
  const int tid = threadIdx.x;
  const int wid = tid >> 6, lane = tid & 63;
  const long row0 = (long)blockIdx.x * 128, col0 = (long)blockIdx.y * 128;
  const int wm = (wid >> 1) * 64, wn = (wid & 1) * 64;
  f32x4 acc[4][4] = {};
  const int sr = tid >> 2, sk = (tid & 3) * 8;
  const unsigned short* gA = A + (row0 + sr) * lda + sk;
  const unsigned short* gB = Bt + (col0 + sr) * ldb + sk;
  unsigned short* lA = As + wid * 512;
  unsigned short* lB = Bs + wid * 512;
  const int fr = lane & 15, fk = (lane >> 4) * 8;

  for (long kb = 0; kb < K; kb += 32) {
    gload16(gA + kb, lA);
    gload16(gA + kb + 64 * lda, lA + 2048);
    gload16(gB + kb, lB);
    gload16(gB + kb + 64 * ldb, lB + 2048);
    __syncthreads();
    bf16x8 af[4], bq[4];
#pragma unroll
    for (int mt = 0; mt < 4; ++mt)
      af[mt] = *(const bf16x8*)(As + (wm + mt * 16 + fr) * 32 + fk);
#pragma unroll
    for (int nt = 0; nt < 4; ++nt)
      bq[nt] = *(const bf16x8*)(Bs + (wn + nt * 16 + fr) * 32 + fk);
#pragma unroll
    for (int mt = 0; mt < 4; ++mt)
#pragma unroll
      for (int nt = 0; nt < 4; ++nt)
        acc[mt][nt] = __builtin_amdgcn_mfma_f32_16x16x32_bf16(
            af[mt], bq[nt], acc[mt][nt], 0, 0, 0);
    __syncthreads();
  }
  const int fq = lane >> 4;
#pragma unroll
  for (int mt = 0; mt < 4; ++mt) {
#pragma unroll
    for (int nt = 0; nt < 4; ++nt) {
      const long c = col0 + wn + nt * 16 + fr;
      if (c < N) {
        const long rb = row0 + wm + mt * 16 + fq * 4;
#pragma unroll
        for (int rg = 0; rg < 4; ++rg)
          ep_store<EP>(acc[mt][nt][rg], rb + rg, c, ldc, Co, Cob, bias, e0f, e0b);
      }
    }
  }
}

// ---------------- GEMM v2 (128x256, counted vmcnt, swizzled LDS) -----------
// BM=128, BN=256, BK=32. 512 thr = 8 waves (2M x 4N); wave owns 64x64.
// LDS: dbuf x {A [128][32], B [256][32]} bf16, 64B rows, XOR-swizzled 16B
// slots (slot' = slot ^ (row&3)) on BOTH the staged global source and the
// ds_read -> <=4-way bank conflicts. Counted s_waitcnt vmcnt(3): next K-tile's
// 3 global_load_lds stay in flight across raw barriers (no drain stall).

template <int EP>
__global__ __launch_bounds__(512)
void gemm2(const unsigned short* __restrict__ A, long lda,
           const unsigned short* __restrict__ Bt, long ldb, long K, long ldc,
           float* __restrict__ Co, unsigned short* __restrict__ Cob,
           const float* __restrict__ e0f) {
  __shared__ unsigned short As[2][4096];  // 2 x 8KB
  __shared__ unsigned short Bs[2][8192];  // 2 x 16KB
  const int tid = threadIdx.x;
  const int wid = tid >> 6, lane = tid & 63;
  const long row0 = (long)blockIdx.x * 128, col0 = (long)blockIdx.y * 256;
  const int wm = (wid >> 2) * 64, wn = (wid & 3) * 64;
  f32x4 acc[4][4] = {};
  // staging source (pre-swizzled column)
  const int srow = tid >> 2;                       // 0..127
  const int scol = 8 * ((tid & 3) ^ (srow & 3));   // swizzled 16B slot
  const unsigned short* gA = A + (row0 + srow) * lda + scol;
  const unsigned short* gB1 = Bt + (col0 + srow) * ldb + scol;
  const unsigned short* gB2 = gB1 + 128 * ldb;
  const int fr = lane & 15, fc = lane >> 4;        // row-in-frag, 16B slot

#define STAGE2(buf, kb)                                   \
  {                                                       \
    gload16(gA + (kb), &As[buf][0] + wid * 512);          \
    gload16(gB1 + (kb), &Bs[buf][0] + wid * 512);         \
    gload16(gB2 + (kb), &Bs[buf][0] + 4096 + wid * 512);  \
  }

  STAGE2(0, 0)
  const int NT = (int)(K >> 5);
  int cur = 0;
  for (int kt = 0; kt < NT; ++kt) {
    if (kt + 1 < NT) {
      STAGE2(cur ^ 1, (long)(kt + 1) * 32)
      asm volatile("s_waitcnt vmcnt(3)" ::: "memory");
    } else {
      asm volatile("s_waitcnt vmcnt(0)" ::: "memory");
    }
    __builtin_amdgcn_s_barrier();
    asm volatile("" ::: "memory");
    bf16x8 af[4], bq[4];
#pragma unroll
    for (int mt = 0; mt < 4; ++mt) {
      const int r = wm + mt * 16 + fr;
      af[mt] = *(const bf16x8*)(&As[cur][0] + r * 32 + ((fc ^ (r & 3)) * 8));
    }
#pragma unroll
    for (int nt = 0; nt < 4; ++nt) {
      const int r = wn + nt * 16 + fr;
      bq[nt] = *(const bf16x8*)(&Bs[cur][0] + r * 32 + ((fc ^ (r & 3)) * 8));
    }
    __builtin_amdgcn_s_setprio(1);
#pragma unroll
    for (int mt = 0; mt < 4; ++mt)
#pragma unroll
      for (int nt = 0; nt < 4; ++nt)
        acc[mt][nt] = __builtin_amdgcn_mfma_f32_16x16x32_bf16(
            af[mt], bq[nt], acc[mt][nt], 0, 0, 0);
    __builtin_amdgcn_s_setprio(0);
    asm volatile("" ::: "memory");
    __builtin_amdgcn_s_barrier();
    cur ^= 1;
  }
#undef STAGE2
  const int fq = lane >> 4;
#pragma unroll
  for (int mt = 0; mt < 4; ++mt) {
#pragma unroll
    for (int nt = 0; nt < 4; ++nt) {
      const long c = col0 + wn + nt * 16 + fr;
      const long rb = row0 + wm + mt * 16 + fq * 4;
#pragma unroll
      for (int rg = 0; rg < 4; ++rg)
        ep_store<EP>(acc[mt][nt][rg], rb + rg, c, ldc, Co, Cob, nullptr, e0f,
                     nullptr);
    }
  }
}

// ------------------------------ k_post -------------------------------------
__global__ __launch_bounds__(256)
void k_post(unsigned short* __restrict__ kio, unsigned short* __restrict__ abio,
            unsigned short* __restrict__ aao, const float* __restrict__ kkw,
            const float* __restrict__ kaw) {
  const int m = blockIdx.x, tid = threadIdx.x;
  const size_t base = (size_t)m * 2048 + tid * 8;
  us8 k8 = *(const us8*)(kio + base);
  us8 a8 = *(const us8*)(abio + base);
  float kk8[8], ka8[8];
  *(float4*)&kk8[0] = *(const float4*)(kkw + tid * 8);
  *(float4*)&kk8[4] = *(const float4*)(kkw + tid * 8 + 4);
  *(float4*)&ka8[0] = *(const float4*)(kaw + tid * 8);
  *(float4*)&ka8[4] = *(const float4*)(kaw + tid * 8 + 4);
  float kx[8], kv[8], av[8];
  float ss = 0.f;
#pragma unroll
  for (int i = 0; i < 8; ++i) {
    kv[i] = b2f(k8[i]); av[i] = b2f(a8[i]);
    kx[i] = kv[i] * kk8[i]; ss += kx[i] * kx[i];
  }
  ss = red8(ss);
  const float inv = 1.f / fmaxf(sqrtf(ss), 1e-12f);
  us8 kh8, aa8, bb8;
#pragma unroll
  for (int i = 0; i < 8; ++i) {
    const float kkn = kx[i] * inv;
    kh8[i] = f2b(kv[i] * (1.f + (av[i] - 1.f) * ka8[i]));
    aa8[i] = f2b(-kkn);
    bb8[i] = f2b(kkn * av[i]);
  }
  *(us8*)(kio + base) = kh8;
  *(us8*)(aao + base) = aa8;
  *(us8*)(abio + base) = bb8;
}

// ------------------------------ WKV scan (R6) -------------------------------

DEV float red16(float x) {  // all-lanes sum within each 16-lane row
  union { float f; int i; } a, r;
  a.f = x; r.i = __builtin_amdgcn_update_dpp(0, a.i, 0xB1, 0xf, 0xf, true);
  x += r.f;
  a.f = x; r.i = __builtin_amdgcn_update_dpp(0, a.i, 0x4E, 0xf, 0xf, true);
  x += r.f;
  a.f = x; r.i = __builtin_amdgcn_update_dpp(0, a.i, 0x124, 0xf, 0xf, true);
  x += r.f;
  a.f = x; r.i = __builtin_amdgcn_update_dpp(0, a.i, 0x128, 0xf, 0xf, true);
  x += r.f;
  return x;
}

DEV void cv4(const uint2 q, float* o) {
  union { unsigned u; float f; } t;
  t.u = q.x << 16;          o[0] = t.f;
  t.u = q.x & 0xffff0000u;  o[1] = t.f;
  t.u = q.y << 16;          o[2] = t.f;
  t.u = q.y & 0xffff0000u;  o[3] = t.f;
}

__global__ __launch_bounds__(64)
void k_scan(const unsigned short* __restrict__ rp,
            const unsigned short* __restrict__ kp,
            const unsigned short* __restrict__ vp,
            const float* __restrict__ wp,
            const unsigned short* __restrict__ ap,
            const unsigned short* __restrict__ bp,
            const float* __restrict__ s0, unsigned short* __restrict__ yout,
            float* __restrict__ snew) {
  __shared__ float4 slots[8][49];
  __shared__ unsigned short ylds[1024][4];
  const int lane = threadIdx.x;
  const int bh = blockIdx.x & 127;
  const int rq = blockIdx.x >> 7;
  const int b = bh >> 5, h = bh & 31;
  const int kg = lane & 15, rl = lane >> 4;
  const int v = rq * 4 + rl, ks = kg * 4;
  const size_t off_bh = (size_t)b * 1024 * 2048 + (size_t)h * 64;

  float S[4];
  *(float4*)&S[0] = *(const float4*)(s0 + (((size_t)bh * 64 + v) * 64 + ks));

  const char* gp = nullptr;
  size_t gstep = 0;
  if (lane < 49) {
    if (lane < 32) {
      const int arr = lane >> 3, sub = lane & 7;
      const unsigned short* base = arr == 0 ? rp : arr == 1 ? kp
                                 : arr == 2 ? ap : bp;
      gp = (const char*)(base + off_bh + sub * 8);
      gstep = 4096;
    } else if (lane < 48) {
      gp = (const char*)(wp + off_bh + (lane - 32) * 4);
      gstep = 8192;
    } else {
      gp = (const char*)(vp + off_bh + (rq & ~1) * 4);
      gstep = 4096;
    }
  }
#pragma unroll
  for (int s = 0; s < 8; ++s) {
    if (lane < 49) gload16(gp, &slots[s][0]);
    gp += gstep;
  }

  for (int t = 0; t < 1024; ++t) {
    asm volatile("s_waitcnt vmcnt(7)" ::: "memory");
    const int sl = t & 7;
    const char* sb = (const char*)&slots[sl][0];
    uint2 r2 = *(const uint2*)(sb + kg * 8);
    uint2 k2 = *(const uint2*)(sb + 128 + kg * 8);
    uint2 a2 = *(const uint2*)(sb + 256 + kg * 8);
    uint2 b2 = *(const uint2*)(sb + 384 + kg * 8);
    float4 wf = *(const float4*)(sb + 512 + kg * 16);
    const unsigned short vfu =
        *(const unsigned short*)(sb + 768 + ((rq & 1) * 4 + rl) * 2);
    asm volatile("s_waitcnt lgkmcnt(0)" ::: "memory");
    if (lane < 49) gload16(gp, &slots[sl][0]);
    if (t < 1015) gp += gstep;

    float rr[4], kk[4], av[4], bv[4];
    cv4(r2, rr); cv4(k2, kk); cv4(a2, av); cv4(b2, bv);
    const float vv = b2f(vfu);
    float sa = S[0] * av[0] + S[1] * av[1] + S[2] * av[2] + S[3] * av[3];
    sa = red16(sa);
    float y;
    S[0] = S[0] * wf.x + sa * bv[0] + vv * kk[0]; y  = S[0] * rr[0];
    S[1] = S[1] * wf.y + sa * bv[1] + vv * kk[1]; y += S[1] * rr[1];
    S[2] = S[2] * wf.z + sa * bv[2] + vv * kk[2]; y += S[2] * rr[2];
    S[3] = S[3] * wf.w + sa * bv[3] + vv * kk[3]; y += S[3] * rr[3];
    y = red16(y);
    if (kg == 0) ylds[t][rl] = f2b(y);
  }

  *(float4*)(snew + (((size_t)bh * 64 + v) * 64 + ks)) = *(const float4*)&S[0];
  asm volatile("s_waitcnt lgkmcnt(0)" ::: "memory");
#pragma unroll 4
  for (int it = 0; it < 16; ++it) {
    const int t = lane + it * 64;
    const uint2 val = *(const uint2*)&ylds[t][0];
    *(uint2*)(yout + off_bh + (size_t)t * 2048 + rq * 4) = val;
  }
}

// ---------------------- GroupNorm + resid + gate ---------------------------

__global__ __launch_bounds__(256)
void k_gn(const unsigned short* __restrict__ y, const unsigned short* __restrict__ r,
          const unsigned short* __restrict__ kh, const unsigned short* __restrict__ vf,
          const unsigned short* __restrict__ g, const float* __restrict__ rk,
          const float* __restrict__ lw, const float* __restrict__ lb,
          unsigned short* __restrict__ ywg) {
  const int m = blockIdx.x, tid = threadIdx.x;
  const size_t base = (size_t)m * 2048 + tid * 8;
  us8 y8 = *(const us8*)(y + base);
  us8 r8 = *(const us8*)(r + base);
  us8 k8 = *(const us8*)(kh + base);
  us8 v8 = *(const us8*)(vf + base);
  us8 g8 = *(const us8*)(g + base);
  float yv[8];
  float rkv[8];
  *(float4*)&rkv[0] = *(const float4*)(rk + tid * 8);
  *(float4*)&rkv[4] = *(const float4*)(rk + tid * 8 + 4);
  float sy = 0.f, sd = 0.f;
#pragma unroll
  for (int i = 0; i < 8; ++i) {
    yv[i] = b2f(y8[i]);
    sy += yv[i];
    sd += b2f(r8[i]) * b2f(k8[i]) * rkv[i];
  }
  sy = red8(sy);
  sd = red8(sd);
  const float mu = sy * (1.f / 64.f);
  float sq = 0.f;
#pragma unroll
  for (int i = 0; i < 8; ++i) { const float d = yv[i] - mu; sq += d * d; }
  sq = red8(sq);
  const float rstd = rsqrtf(sq * (1.f / 64.f) + 64e-5f);
  us8 o8;
#pragma unroll
  for (int i = 0; i < 8; ++i) {
    const int c = tid * 8 + i;
    const float gn = (yv[i] - mu) * rstd * lw[c] + lb[c];
    o8[i] = f2b((gn + sd * b2f(v8[i])) * b2f(g8[i]));
  }
  *(us8*)(ywg + base) = o8;
}

// ------------------------------ launch -------------------------------------

extern "C" void kernel_launch(void* const* d_in, const int* in_sizes, int n_in,
                              void* d_out, int out_size, void* d_ws,
                              size_t ws_size, hipStream_t stream) {
  (void)in_sizes; (void)n_in; (void)out_size; (void)ws_size;
  const float* x         = (const float*)d_in[0];
  const float* v_first   = (const float*)d_in[1];
  const float* att_shift = (const float*)d_in[2];
  const float* ffn_shift = (const float*)d_in[3];
  const float* wkv0      = (const float*)d_in[4];
  const float* ln1w = (const float*)d_in[5];
  const float* ln1b = (const float*)d_in[6];
  const float* ln2w = (const float*)d_in[7];
  const float* ln2b = (const float*)d_in[8];
  const float* x_r = (const float*)d_in[9];
  const float* x_w = (const float*)d_in[10];
  const float* x_k = (const float*)d_in[11];
  const float* x_v = (const float*)d_in[12];
  const float* x_a = (const float*)d_in[13];
  const float* x_g = (const float*)d_in[14];
  const float* Wr = (const float*)d_in[15];
  const float* Wk = (const float*)d_in[16];
  const float* Wv = (const float*)d_in[17];
  const float* Wo = (const float*)d_in[18];
  const float* w0 = (const float*)d_in[19];
  const float* w1 = (const float*)d_in[20];
  const float* w2 = (const float*)d_in[21];
  const float* v0 = (const float*)d_in[22];
  const float* v1 = (const float*)d_in[23];
  const float* v2 = (const float*)d_in[24];
  const float* a0 = (const float*)d_in[25];
  const float* a1 = (const float*)d_in[26];
  const float* a2 = (const float*)d_in[27];
  const float* g1 = (const float*)d_in[28];
  const float* g2 = (const float*)d_in[29];
  const float* k_k = (const float*)d_in[30];
  const float* k_a = (const float*)d_in[31];
  const float* r_k = (const float*)d_in[32];
  const float* lnxw = (const float*)d_in[33];
  const float* lnxb = (const float*)d_in[34];
  const float* ffn_xk = (const float*)d_in[35];
  const float* Wkf = (const float*)d_in[36];
  const float* Wvf = (const float*)d_in[37];

  char* ws = (char*)d_ws;
  constexpr size_t OFF_TWR   = 0;
  constexpr size_t OFF_TWK   = 8388608;
  constexpr size_t OFF_TWV   = 16777216;
  constexpr size_t OFF_TWO   = 25165824;
  constexpr size_t OFF_TW2   = 33554432;
  constexpr size_t OFF_TA2   = 33816576;
  constexpr size_t OFF_TV2   = 34078720;
  constexpr size_t OFF_TG2   = 34209792;
  constexpr size_t OFF_TWCAT = 34734080;
  constexpr size_t OFF_HACT  = 37879808;
  constexpr size_t OFF_GBUF  = 40239104;
  constexpr size_t OFF_WH    = 57016320;
  constexpr size_t OFF_R     = 90570752;
  constexpr size_t OFF_KH    = 107347968;
  constexpr size_t OFF_VF    = 124125184;
  constexpr size_t OFF_AA    = 140902400;
  constexpr size_t OFF_BB    = 157679616;

  unsigned short* tWr = (unsigned short*)(ws + OFF_TWR);
  unsigned short* tWk = (unsigned short*)(ws + OFF_TWK);
  unsigned short* tWv = (unsigned short*)(ws + OFF_TWV);
  unsigned short* tWo = (unsigned short*)(ws + OFF_TWO);
  unsigned short* tw2 = (unsigned short*)(ws + OFF_TW2);
  unsigned short* ta2 = (unsigned short*)(ws + OFF_TA2);
  unsigned short* tv2 = (unsigned short*)(ws + OFF_TV2);
  unsigned short* tg2 = (unsigned short*)(ws + OFF_TG2);
  unsigned short* tWcat = (unsigned short*)(ws + OFF_TWCAT);
  unsigned short* Hact  = (unsigned short*)(ws + OFF_HACT);
  unsigned short* gbuf  = (unsigned short*)(ws + OFF_GBUF);
  unsigned short* tWvfh = (unsigned short*)(ws + OFF_GBUF);
  unsigned short* act2  = (unsigned short*)(ws + OFF_WH);
  float*          whb   = (float*)(ws + OFF_WH);
  unsigned short* ywg   = (unsigned short*)(ws + OFF_WH);
  unsigned short* kf    = (unsigned short*)(ws + OFF_WH);
  unsigned short* bxr   = (unsigned short*)(ws + OFF_AA);
  unsigned short* bxk   = (unsigned short*)(ws + OFF_BB);
  unsigned short* bxv   = (unsigned short*)(ws + OFF_VF);
  unsigned short* rbuf  = (unsigned short*)(ws + OFF_R);
  unsigned short* khb   = (unsigned short*)(ws + OFF_KH);
  unsigned short* vfb   = (unsigned short*)(ws + OFF_VF);
  unsigned short* aab   = (unsigned short*)(ws + OFF_AA);
  unsigned short* bbb   = (unsigned short*)(ws + OFF_BB);
  unsigned short* vraw  = (unsigned short*)(ws + OFF_AA);
  unsigned short* abuf  = (unsigned short*)(ws + OFF_BB);
  float*          x1    = (float*)(ws + OFF_R);
  unsigned short* xkf   = (unsigned short*)(ws + OFF_VF);
  unsigned short* tWkf  = (unsigned short*)(ws + OFF_AA);
  float* out = (float*)d_out;
  float* snew = out + 8388608;

  const dim3 tb(32, 8);
  // ---- weight prep ----
  k_transpose<<<dim3(64, 64), tb, 0, stream>>>(Wr, tWr, 2048, 2048);
  k_transpose<<<dim3(64, 64), tb, 0, stream>>>(Wk, tWk, 2048, 2048);
  k_transpose<<<dim3(64, 64), tb, 0, stream>>>(Wv, tWv, 2048, 2048);
  k_transpose<<<dim3(64, 64), tb, 0, stream>>>(Wo, tWo, 2048, 2048);
  k_transpose<<<dim3(64, 2), tb, 0, stream>>>(w2, tw2, 64, 2048);
  k_transpose<<<dim3(64, 2), tb, 0, stream>>>(a2, ta2, 64, 2048);
  k_transpose<<<dim3(64, 1), tb, 0, stream>>>(v2, tv2, 32, 2048);
  k_transpose<<<dim3(64, 4), tb, 0, stream>>>(g2, tg2, 128, 2048);
  k_wcat<<<6144, 256, 0, stream>>>(w1, a1, v1, g1, x_w, x_a, x_v, x_g, tWcat);

  // ---- TimeMix front ----
  k_ln1_mix<<<4096, 256, 0, stream>>>(x, att_shift, ln1w, ln1b, x_r, x_k, x_v,
                                      act2, bxr, bxk, bxv);
  gemm2<EP_B16><<<dim3(32, 8), 512, 0, stream>>>(
      bxr, 2048, tWr, 2048, 2048, 2048, nullptr, rbuf, nullptr);
  gemm2<EP_B16><<<dim3(32, 8), 512, 0, stream>>>(
      bxk, 2048, tWk, 2048, 2048, 2048, nullptr, khb, nullptr);
  gemm2<EP_B16><<<dim3(32, 8), 512, 0, stream>>>(
      bxv, 2048, tWv, 2048, 2048, 2048, nullptr, vraw, nullptr);
  gemm_bt<EP_HACT><<<dim3(32, 3), 256, 0, stream>>>(
      act2, 4096, tWcat, 4096, 288, 4096, 288, nullptr, Hact, nullptr, nullptr, nullptr);
  gemm_bt<EP_W><<<dim3(32, 16), 256, 0, stream>>>(
      Hact + 0, 288, tw2, 64, 2048, 64, 2048, whb, nullptr, w0, nullptr, nullptr);
  gemm_bt<EP_AB16><<<dim3(32, 16), 256, 0, stream>>>(
      Hact + 64, 288, ta2, 64, 2048, 64, 2048, nullptr, abuf, a0, nullptr, nullptr);
  gemm_bt<EP_VGB16><<<dim3(32, 16), 256, 0, stream>>>(
      Hact + 128, 288, tv2, 32, 2048, 32, 2048, nullptr, vfb, v0, v_first, vraw);
  gemm_bt<EP_B16><<<dim3(32, 16), 256, 0, stream>>>(
      Hact + 160, 288, tg2, 128, 2048, 128, 2048, nullptr, gbuf, nullptr, nullptr, nullptr);
  k_post<<<4096, 256, 0, stream>>>(khb, abuf, aab, k_k, k_a);

  // ---- WKV scan ----
  k_scan<<<2048, 64, 0, stream>>>(rbuf, khb, vfb, whb, aab, bbb, wkv0,
                                  (unsigned short*)out, snew);
  k_gn<<<4096, 256, 0, stream>>>((const unsigned short*)out, rbuf, khb, vfb,
                                 gbuf, r_k, lnxw, lnxb, ywg);

  // ---- Wo projection (+x) -> x1 ----
  gemm2<EP_ADDF><<<dim3(32, 8), 512, 0, stream>>>(
      ywg, 2048, tWo, 2048, 2048, 2048, x1, nullptr, x);

  // ---- ChannelMix (two DFF halves) ----
  k_ln2_mix<<<4096, 256, 0, stream>>>(x1, ffn_shift, ln2w, ln2b, ffn_xk, xkf);
  k_transpose<<<dim3(256, 64), tb, 0, stream>>>(Wkf, tWkf, 2048, 8192);
  gemm2<EP_RELU2><<<dim3(32, 16), 512, 0, stream>>>(
      xkf, 2048, tWkf, 2048, 2048, 4096, nullptr, kf, nullptr);
  k_transpose<<<dim3(64, 128), tb, 0, stream>>>(Wvf, tWvfh, 4096, 2048);
  gemm2<EP_ADDF><<<dim3(32, 8), 512, 0, stream>>>(
      kf, 4096, tWvfh, 4096, 4096, 2048, out, nullptr, x1);
  gemm2<EP_RELU2><<<dim3(32, 16), 512, 0, stream>>>(
      xkf, 2048, tWkf + (size_t)4096 * 2048, 2048, 2048, 4096, nullptr, kf, nullptr);
  k_transpose<<<dim3(64, 128), tb, 0, stream>>>(Wvf + (size_t)4096 * 2048, tWvfh,
                                                4096, 2048);
  gemm2<EP_ADDF><<<dim3(32, 8), 512, 0, stream>>>(
      kf, 4096, tWvfh, 4096, 4096, 2048, out, nullptr, out);
}